// Round 12
// baseline (244.651 us; speedup 1.0000x reference)
//
#include <hip/hip_runtime.h>

#define B_ 2
#define T_ 4096
#define C_ 768
#define H_ 12
#define D_ 64
#define QTASK 96       /* tasks per XCD queue: 3 bh * 32 qi */

typedef __attribute__((ext_vector_type(8))) short bf16x8;
typedef __attribute__((ext_vector_type(4))) float f32x4;
typedef __attribute__((ext_vector_type(16))) float f32x16;

__device__ __forceinline__ unsigned short f2bf(float f) {
  union { float f; unsigned u; } v; v.f = f;
  unsigned r = v.u + 0x7fffu + ((v.u >> 16) & 1u);
  return (unsigned short)(r >> 16);
}

__device__ __forceinline__ float exp2_hw(float x) {
  float r;
  asm("v_exp_f32 %0, %1" : "=v"(r) : "v"(x));
  return r;
}

__device__ __forceinline__ void gll16(const void* g, void* l) {
  __builtin_amdgcn_global_load_lds((const __attribute__((address_space(1))) void*)g,
                                   (__attribute__((address_space(3))) void*)l, 16, 0, 0);
}

#define MAX3(a, b, c) fmaxf(fmaxf((a), (b)), (c))

// ---------------- cast kernels ----------------

// f32 -> bf16 (coalesced); resets the 8 task-queue counters
__global__ __launch_bounds__(256) void cast_bf16_k(const float* __restrict__ in,
                                                   unsigned short* __restrict__ out, int n4,
                                                   unsigned* __restrict__ cnt) {
  int i = blockIdx.x * 256 + threadIdx.x;
  if (i < 128) cnt[i] = 0u;
  if (i >= n4) return;
  float4 v = ((const float4*)in)[i];
  union { unsigned short s[4]; unsigned long long u; } o;
  o.s[0] = f2bf(v.x); o.s[1] = f2bf(v.y); o.s[2] = f2bf(v.z); o.s[3] = f2bf(v.w);
  ((unsigned long long*)out)[i] = o.u;
}

// in [R][C] f32 -> out [C][R] bf16, 64x64 tiles via LDS (coalesced both sides)
__global__ __launch_bounds__(256) void tpose_cast_k(const float* __restrict__ in,
                                                    unsigned short* __restrict__ out,
                                                    int R, int C) {
  __shared__ unsigned short t[64][65];
  const int c0 = blockIdx.x * 64, r0 = blockIdx.y * 64;
  const int tr = threadIdx.x >> 6, tc = threadIdx.x & 63;
#pragma unroll
  for (int i = 0; i < 16; ++i) {
    int r = i * 4 + tr;
    t[r][tc] = f2bf(in[(size_t)(r0 + r) * C + c0 + tc]);
  }
  __syncthreads();
#pragma unroll
  for (int i = 0; i < 16; ++i) {
    int c = i * 4 + tr;
    out[(size_t)(c0 + c) * R + r0 + tc] = t[tc][c];
  }
}

// ---------------- GEMM (R5 structure, unchanged) ----------------

#define QSCALE 0.1803368801111243f /* 0.125 * log2(e) */

template <int MODE>
__global__ __launch_bounds__(256) void gemm_k(const unsigned short* __restrict__ A,
                                              const unsigned short* __restrict__ Bt,
                                              int K,
                                              unsigned short* __restrict__ q_out,
                                              unsigned short* __restrict__ k_out,
                                              unsigned short* __restrict__ vt_out,
                                              float* __restrict__ f_out,
                                              const float* __restrict__ bias) {
  __shared__ short a_lds[2][128 * 32];
  __shared__ short b_lds[2][128 * 32];
  const int tid = threadIdx.x;
  const int wave = tid >> 6, lane = tid & 63;
  const int wm = wave >> 1, wn = wave & 1;
  const int lr = lane & 15, lc = lane >> 4;

  const int id = blockIdx.x;
  const int xcd = id & 7, idc = id >> 3;
  const int bx = xcd * 8 + (idc & 7);
  const int by = idc >> 3;
  const int m0 = bx * 128, n0 = by * 128;

  f32x4 acc[4][4];
  for (int mi = 0; mi < 4; ++mi)
    for (int ni = 0; ni < 4; ++ni) acc[mi][ni] = (f32x4){0.f, 0.f, 0.f, 0.f};

  const unsigned short *ap[2], *bp[2];
  int lb[2];
#pragma unroll
  for (int p = 0; p < 2; ++p) {
    int chunk = p * 256 + wave * 64 + lane;
    int r = chunk >> 2, cc = chunk & 3;
    int c = cc ^ ((r >> 1) & 3);
    ap[p] = A + (size_t)(m0 + r) * K + c * 8;
    bp[p] = Bt + (size_t)(n0 + r) * K + c * 8;
    lb[p] = (p * 256 + wave * 64) * 8;
  }

  const int nks = K >> 5;
#pragma unroll
  for (int p = 0; p < 2; ++p) {
    gll16(ap[p], &a_lds[0][lb[p]]);
    gll16(bp[p], &b_lds[0][lb[p]]);
    ap[p] += 32; bp[p] += 32;
  }

  for (int ks = 0; ks < nks; ++ks) {
    const int buf = ks & 1;
    __builtin_amdgcn_s_barrier();
    __builtin_amdgcn_sched_barrier(0);
    if (ks + 1 < nks) {
#pragma unroll
      for (int p = 0; p < 2; ++p) {
        gll16(ap[p], &a_lds[buf ^ 1][lb[p]]);
        gll16(bp[p], &b_lds[buf ^ 1][lb[p]]);
        ap[p] += 32; bp[p] += 32;
      }
      asm volatile("s_waitcnt vmcnt(4)" ::: "memory");
    } else {
      asm volatile("s_waitcnt vmcnt(0)" ::: "memory");
    }
    __builtin_amdgcn_sched_barrier(0);
    __builtin_amdgcn_s_barrier();
    __builtin_amdgcn_sched_barrier(0);

    bf16x8 af[4], bfrag[4];
#pragma unroll
    for (int mi = 0; mi < 4; ++mi) {
      int r = wm * 64 + mi * 16 + lr;
      af[mi] = *(const bf16x8*)&a_lds[buf][r * 32 + (lc ^ ((r >> 1) & 3)) * 8];
    }
#pragma unroll
    for (int ni = 0; ni < 4; ++ni) {
      int r = wn * 64 + ni * 16 + lr;
      bfrag[ni] = *(const bf16x8*)&b_lds[buf][r * 32 + (lc ^ ((r >> 1) & 3)) * 8];
    }
    __builtin_amdgcn_s_setprio(1);
#pragma unroll
    for (int mi = 0; mi < 4; ++mi)
#pragma unroll
      for (int ni = 0; ni < 4; ++ni)
        acc[mi][ni] = __builtin_amdgcn_mfma_f32_16x16x32_bf16(af[mi], bfrag[ni], acc[mi][ni], 0, 0, 0);
    __builtin_amdgcn_s_setprio(0);
  }

  if (MODE == 0) {
    const int nn0 = n0 + wn * 64 + lr;
    const int which = n0 / 768;
#pragma unroll
    for (int mi = 0; mi < 4; ++mi)
#pragma unroll
      for (int ni = 0; ni < 4; ++ni) {
        int nn = nn0 + ni * 16;
        int rem = nn - which * 768;
        int h = rem >> 6, d = rem & 63;
        int t0v = m0 + wm * 64 + mi * 16 + lc * 4;
        int b = t0v >> 12, t = t0v & (T_ - 1);
        size_t bh = (size_t)(b * H_ + h);
        if (which == 2) {
          unsigned u0, u1;
          asm("v_cvt_pk_bf16_f32 %0, %1, %2" : "=v"(u0) : "v"(acc[mi][ni][0]), "v"(acc[mi][ni][1]));
          asm("v_cvt_pk_bf16_f32 %0, %1, %2" : "=v"(u1) : "v"(acc[mi][ni][2]), "v"(acc[mi][ni][3]));
          uint2 u = {u0, u1};
          *(uint2*)&vt_out[(bh * D_ + d) * T_ + t] = u;
        } else {
#pragma unroll
          for (int r = 0; r < 4; ++r) {
            float av = acc[mi][ni][r];
            if (which == 0) av *= QSCALE;
            unsigned short val = f2bf(av);
            if (which == 0) q_out[(bh * T_ + t + r) * D_ + d] = val;
            else            k_out[(bh * T_ + t + r) * D_ + d] = val;
          }
        }
      }
  } else {
#pragma unroll
    for (int mi = 0; mi < 4; ++mi)
#pragma unroll
      for (int ni = 0; ni < 4; ++ni) {
        int nn = n0 + wn * 64 + ni * 16 + lr;
        float bv = bias[nn];
#pragma unroll
        for (int r = 0; r < 4; ++r) {
          int m = m0 + wm * 64 + mi * 16 + lc * 4 + r;
          f_out[(size_t)m * C_ + nn] = acc[mi][ni][r] + bv;
        }
      }
  }
}

// ---------------- flash attention v12: KVBLK=128, MFMA/VALU software pipeline ----------------
// Straight-line iteration: QK0; QK1; SM0; PV0; SM1; PV1 — QK1 issues before SM0
// (SM0 VALU runs under QK MFMA latency); SM1 VALU (indep of accT when no rescale)
// fills PV0's MFMA-latency gaps. v_max3 trees. Per-XCD dynamic LPT queues.

#define PACK8(SV, PW, O)                                                          \
  do {                                                                            \
    unsigned w0, w1, w2, w3, w4, w5, w6, w7;                                      \
    asm("v_cvt_pk_bf16_f32 %0, %1, %2" : "=v"(w0) : "v"(SV[0]), "v"(SV[1]));      \
    asm("v_cvt_pk_bf16_f32 %0, %1, %2" : "=v"(w1) : "v"(SV[2]), "v"(SV[3]));      \
    asm("v_cvt_pk_bf16_f32 %0, %1, %2" : "=v"(w2) : "v"(SV[4]), "v"(SV[5]));      \
    asm("v_cvt_pk_bf16_f32 %0, %1, %2" : "=v"(w3) : "v"(SV[6]), "v"(SV[7]));      \
    asm("v_cvt_pk_bf16_f32 %0, %1, %2" : "=v"(w4) : "v"(SV[8]), "v"(SV[9]));      \
    asm("v_cvt_pk_bf16_f32 %0, %1, %2" : "=v"(w5) : "v"(SV[10]), "v"(SV[11]));    \
    asm("v_cvt_pk_bf16_f32 %0, %1, %2" : "=v"(w6) : "v"(SV[12]), "v"(SV[13]));    \
    asm("v_cvt_pk_bf16_f32 %0, %1, %2" : "=v"(w7) : "v"(SV[14]), "v"(SV[15]));    \
    asm("v_permlane32_swap_b32 %0, %1" : "+v"(w0), "+v"(w2));                     \
    asm("v_permlane32_swap_b32 %0, %1" : "+v"(w1), "+v"(w3));                     \
    asm("v_permlane32_swap_b32 %0, %1" : "+v"(w4), "+v"(w6));                     \
    asm("v_permlane32_swap_b32 %0, %1" : "+v"(w5), "+v"(w7));                     \
    PW[(O) + 0] = w0; PW[(O) + 1] = w1; PW[(O) + 2] = w2; PW[(O) + 3] = w3;       \
    PW[(O) + 4] = w4; PW[(O) + 5] = w5; PW[(O) + 6] = w6; PW[(O) + 7] = w7;       \
  } while (0)

__global__ __launch_bounds__(256) void flash12_k(const unsigned short* __restrict__ Qg,
                                                 const unsigned short* __restrict__ Kg,
                                                 const unsigned short* __restrict__ Vtg,
                                                 unsigned short* __restrict__ Og,
                                                 unsigned* __restrict__ cnt) {
  __shared__ short k_lds[2][16 * 512];   // 32 KB
  __shared__ short vt_lds[2][16 * 512];  // 32 KB
  __shared__ int task_s;

  const int tid = threadIdx.x;
  const int wave = tid >> 6, lane = tid & 63;
  const int lq = lane & 31, hi = lane >> 5;
  const int xq = blockIdx.x & 7;
  unsigned* myq = cnt + xq * 16;

  for (;;) {
    if (tid == 0) task_s = (int)atomicAdd(myq, 1u);
    __syncthreads();
    const int task = task_s;
    if (task >= QTASK) return;

    const int qi = 31 - task / 3;       // LPT: heavy first
    const int bh = xq * 3 + (task - (task / 3) * 3);
    const int qw = qi * 128 + wave * 32;
    const int q_g = qw + lq;

    const size_t kbase = (size_t)bh * T_ * D_;
    const size_t vbase = (size_t)bh * D_ * T_;

    const unsigned short* qrow = Qg + kbase + (size_t)q_g * D_;
    bf16x8 qf[4];
#pragma unroll
    for (int t = 0; t < 4; ++t) qf[t] = *(const bf16x8*)(qrow + t * 16 + hi * 8);

    f32x16 accT0, accT1;
#pragma unroll
    for (int r = 0; r < 16; ++r) { accT0[r] = 0.f; accT1[r] = 0.f; }
    float lvec[8];
#pragma unroll
    for (int r = 0; r < 8; ++r) lvec[r] = 0.f;
    float m = 0.f;

    const int nt = qi + 1;              // 128-key iterations

    // staging: frag f = wave + p*4 (p=0..3 covers f=0..15)
    const unsigned short *kb_p[4], *vb_p[4];
    int lf[4];
#pragma unroll
    for (int p = 0; p < 4; ++p) {
      int f = wave + p * 4;
      int sub = f >> 3, tt = (f >> 1) & 3, h = f & 1;
      kb_p[p] = Kg + kbase + (size_t)(sub * 64 + h * 32 + lq) * D_ + tt * 16 + hi * 8;
      vb_p[p] = Vtg + vbase + (size_t)(h * 32 + lq) * T_ + sub * 64 + tt * 16 + hi * 8;
      lf[p] = f * 512;
    }

    auto stage = [&](int it, int sb) {
#pragma unroll
      for (int p = 0; p < 4; ++p) {
        gll16(kb_p[p] + (size_t)it * 128 * D_, &k_lds[sb][lf[p]]);
        gll16(vb_p[p] + it * 128, &vt_lds[sb][lf[p]]);
      }
    };

    // softmax+pack on a pair of score tiles (32 scores/lane), keys at kvo..kvo+63
    auto sm_pack = [&](f32x16& sa, f32x16& sb, int kvo, unsigned* pwp) {
      if (kvo + 63 > qw) {
#pragma unroll
        for (int r = 0; r < 16; ++r) {
          int key0 = kvo + ((r & 3) + 8 * (r >> 2) + 4 * hi);
          if (key0 > q_g) sa[r] = -INFINITY;
          if (key0 + 32 > q_g) sb[r] = -INFINITY;
        }
      }
      float a0 = MAX3(sa[0], sa[1], sa[2]);
      float a1 = MAX3(sa[3], sa[4], sa[5]);
      float a2 = MAX3(sa[6], sa[7], sa[8]);
      float a3 = MAX3(sa[9], sa[10], sa[11]);
      float a4 = MAX3(sa[12], sa[13], sa[14]);
      float b0 = MAX3(sb[0], sb[1], sb[2]);
      float b1 = MAX3(sb[3], sb[4], sb[5]);
      float b2 = MAX3(sb[6], sb[7], sb[8]);
      float b3 = MAX3(sb[9], sb[10], sb[11]);
      float b4 = MAX3(sb[12], sb[13], sb[14]);
      float c0 = MAX3(a0, a1, a2);
      float c1 = MAX3(a3, a4, sa[15]);
      float c2 = MAX3(b0, b1, b2);
      float c3 = MAX3(b3, b4, sb[15]);
      float rx = fmaxf(fmaxf(c0, c1), fmaxf(c2, c3));
      rx = fmaxf(rx, __shfl_xor(rx, 32));
      if (!__all(rx <= 8.f)) {
        float dlt = fmaxf(rx, 0.f);
        float al = exp2_hw(-dlt);
        m += dlt;
#pragma unroll
        for (int r = 0; r < 16; ++r) { accT0[r] *= al; accT1[r] *= al; }
#pragma unroll
        for (int r = 0; r < 8; ++r) lvec[r] *= al;
#pragma unroll
        for (int r = 0; r < 16; ++r) { sa[r] -= dlt; sb[r] -= dlt; }
      }
#pragma unroll
      for (int r = 0; r < 16; ++r) sa[r] = exp2_hw(sa[r]);
#pragma unroll
      for (int r = 0; r < 16; ++r) sb[r] = exp2_hw(sb[r]);
#pragma unroll
      for (int r = 0; r < 8; ++r) lvec[r] += (sa[r] + sb[r]) + (sa[r + 8] + sb[r + 8]);
      PACK8(sa, pwp, 0);
      PACK8(sb, pwp, 8);
    };

    stage(0, 0);

    for (int j = 0; j < nt; ++j) {
      const int kv = j * 128;
      const int buf = j & 1;

      __builtin_amdgcn_s_barrier();     // all waves done compute(j-1)
      __builtin_amdgcn_sched_barrier(0);
      if (j + 1 < nt) {
        stage(j + 1, buf ^ 1);
        asm volatile("s_waitcnt vmcnt(8)" ::: "memory");  // stage(j) landed
      } else {
        asm volatile("s_waitcnt vmcnt(0)" ::: "memory");
      }
      __builtin_amdgcn_sched_barrier(0);
      __builtin_amdgcn_s_barrier();     // buf[j&1] ready for everyone
      __builtin_amdgcn_sched_barrier(0);

      const bool act1 = (kv + 64 <= qw + 31);
      const float mb = m;
      const float negmb = -mb;

      if (act1) {
        // ---- QK0 + QK1 back-to-back (independent chains; SM0 runs under their latency) ----
        f32x16 s0, s1, s2, s3;
#pragma unroll
        for (int r = 0; r < 16; ++r) { s0[r] = negmb; s1[r] = negmb; s2[r] = negmb; s3[r] = negmb; }
        __builtin_amdgcn_s_setprio(1);
#pragma unroll
        for (int t = 0; t < 4; ++t) {
          bf16x8 kf0 = *(const bf16x8*)&k_lds[buf][(t * 2 + 0) * 512 + lane * 8];
          bf16x8 kf1 = *(const bf16x8*)&k_lds[buf][(t * 2 + 1) * 512 + lane * 8];
          s0 = __builtin_amdgcn_mfma_f32_32x32x16_bf16(kf0, qf[t], s0, 0, 0, 0);
          s1 = __builtin_amdgcn_mfma_f32_32x32x16_bf16(kf1, qf[t], s1, 0, 0, 0);
        }
#pragma unroll
        for (int t = 0; t < 4; ++t) {
          bf16x8 kf0 = *(const bf16x8*)&k_lds[buf][(8 + t * 2 + 0) * 512 + lane * 8];
          bf16x8 kf1 = *(const bf16x8*)&k_lds[buf][(8 + t * 2 + 1) * 512 + lane * 8];
          s2 = __builtin_amdgcn_mfma_f32_32x32x16_bf16(kf0, qf[t], s2, 0, 0, 0);
          s3 = __builtin_amdgcn_mfma_f32_32x32x16_bf16(kf1, qf[t], s3, 0, 0, 0);
        }
        __builtin_amdgcn_s_setprio(0);

        // ---- SM0 (s2/s3 untouched — overlaps QK latency) ----
        unsigned pwu0[16];
        sm_pack(s0, s1, kv, pwu0);

        // ---- PV0; SM1 VALU fills PV0 MFMA-latency gaps ----
        __builtin_amdgcn_s_setprio(1);
#pragma unroll
        for (int ks = 0; ks < 4; ++ks) {
          union { unsigned u[4]; bf16x8 v; } pb;
          pb.u[0] = pwu0[ks * 4 + 0]; pb.u[1] = pwu0[ks * 4 + 1];
          pb.u[2] = pwu0[ks * 4 + 2]; pb.u[3] = pwu0[ks * 4 + 3];
          bf16x8 vf0 = *(const bf16x8*)&vt_lds[buf][(ks * 2 + 0) * 512 + lane * 8];
          bf16x8 vf1 = *(const bf16x8*)&vt_lds[buf][(ks * 2 + 1) * 512 + lane * 8];
          accT0 = __builtin_amdgcn_mfma_f32_32x32x16_bf16(vf0, pb.v, accT0, 0, 0, 0);
          accT1 = __builtin_amdgcn_mfma_f32_32x32x16_bf16(vf1, pb.v, accT1, 0, 0, 0);
        }
        __builtin_amdgcn_s_setprio(0);

        // ---- SM1 (adjust base if sub0 rescaled — rare, wave-checked) ----
        float corr = m - mb;
        if (!__all(corr == 0.f)) {
#pragma unroll
          for (int r = 0; r < 16; ++r) { s2[r] -= corr; s3[r] -= corr; }
        }
        unsigned pwu1[16];
        sm_pack(s2, s3, kv + 64, pwu1);

        // ---- PV1 ----
        __builtin_amdgcn_s_setprio(1);
#pragma unroll
        for (int ks = 0; ks < 4; ++ks) {
          union { unsigned u[4]; bf16x8 v; } pb;
          pb.u[0] = pwu1[ks * 4 + 0]; pb.u[1] = pwu1[ks * 4 + 1];
          pb.u[2] = pwu1[ks * 4 + 2]; pb.u[3] = pwu1[ks * 4 + 3];
          bf16x8 vf0 = *(const bf16x8*)&vt_lds[buf][(8 + ks * 2 + 0) * 512 + lane * 8];
          bf16x8 vf1 = *(const bf16x8*)&vt_lds[buf][(8 + ks * 2 + 1) * 512 + lane * 8];
          accT0 = __builtin_amdgcn_mfma_f32_32x32x16_bf16(vf0, pb.v, accT0, 0, 0, 0);
          accT1 = __builtin_amdgcn_mfma_f32_32x32x16_bf16(vf1, pb.v, accT1, 0, 0, 0);
        }
        __builtin_amdgcn_s_setprio(0);
      } else {
        // ---- single active sub-tile ----
        f32x16 s0, s1;
#pragma unroll
        for (int r = 0; r < 16; ++r) { s0[r] = negmb; s1[r] = negmb; }
        __builtin_amdgcn_s_setprio(1);
#pragma unroll
        for (int t = 0; t < 4; ++t) {
          bf16x8 kf0 = *(const bf16x8*)&k_lds[buf][(t * 2 + 0) * 512 + lane * 8];
          bf16x8 kf1 = *(const bf16x8*)&k_lds[buf][(t * 2 + 1) * 512 + lane * 8];
          s0 = __builtin_amdgcn_mfma_f32_32x32x16_bf16(kf0, qf[t], s0, 0, 0, 0);
          s1 = __builtin_amdgcn_mfma_f32_32x32x16_bf16(kf1, qf[t], s1, 0, 0, 0);
        }
        __builtin_amdgcn_s_setprio(0);

        unsigned pwu0[16];
        sm_pack(s0, s1, kv, pwu0);

        __builtin_amdgcn_s_setprio(1);
#pragma unroll
        for (int ks = 0; ks < 4; ++ks) {
          union { unsigned u[4]; bf16x8 v; } pb;
          pb.u[0] = pwu0[ks * 4 + 0]; pb.u[1] = pwu0[ks * 4 + 1];
          pb.u[2] = pwu0[ks * 4 + 2]; pb.u[3] = pwu0[ks * 4 + 3];
          bf16x8 vf0 = *(const bf16x8*)&vt_lds[buf][(ks * 2 + 0) * 512 + lane * 8];
          bf16x8 vf1 = *(const bf16x8*)&vt_lds[buf][(ks * 2 + 1) * 512 + lane * 8];
          accT0 = __builtin_amdgcn_mfma_f32_32x32x16_bf16(vf0, pb.v, accT0, 0, 0, 0);
          accT1 = __builtin_amdgcn_mfma_f32_32x32x16_bf16(vf1, pb.v, accT1, 0, 0, 0);
        }
        __builtin_amdgcn_s_setprio(0);
      }
    }

    // ---- final l reduce + epilogue ----
    float l = 0.f;
#pragma unroll
    for (int r = 0; r < 8; ++r) l += lvec[r];
    l += __shfl_xor(l, 32);
    const float inv = 1.0f / l;
    const int b = bh / H_, h = bh - b * H_;
    unsigned short* orow = Og + ((size_t)b * T_ + q_g) * C_ + h * D_;
#pragma unroll
    for (int g = 0; g < 4; ++g) {
      int d0 = 8 * g + 4 * hi;
      float e0 = accT0[4 * g + 0] * inv, e1 = accT0[4 * g + 1] * inv;
      float e2 = accT0[4 * g + 2] * inv, e3 = accT0[4 * g + 3] * inv;
      float f0 = accT1[4 * g + 0] * inv, f1 = accT1[4 * g + 1] * inv;
      float f2 = accT1[4 * g + 2] * inv, f3 = accT1[4 * g + 3] * inv;
      uint2 ua, ub;
      asm("v_cvt_pk_bf16_f32 %0, %1, %2" : "=v"(ua.x) : "v"(e0), "v"(e1));
      asm("v_cvt_pk_bf16_f32 %0, %1, %2" : "=v"(ua.y) : "v"(e2), "v"(e3));
      asm("v_cvt_pk_bf16_f32 %0, %1, %2" : "=v"(ub.x) : "v"(f0), "v"(f1));
      asm("v_cvt_pk_bf16_f32 %0, %1, %2" : "=v"(ub.y) : "v"(f2), "v"(f3));
      *(uint2*)(orow + d0) = ua;
      *(uint2*)(orow + 32 + d0) = ub;
    }
    __syncthreads();  // quiesce LDS before next pop
  }
}

// ---------------- launcher ----------------

extern "C" void kernel_launch(void* const* d_in, const int* in_sizes, int n_in,
                              void* d_out, int out_size, void* d_ws, size_t ws_size,
                              hipStream_t stream) {
  const float* x     = (const float*)d_in[0];
  const float* Wqkv  = (const float*)d_in[1];
  const float* Wproj = (const float*)d_in[2];
  const float* bproj = (const float*)d_in[3];
  float* out = (float*)d_out;

  char* ws = (char*)d_ws;
  unsigned short* xbf   = (unsigned short*)(ws);
  unsigned short* wqkvt = (unsigned short*)(ws + 12582912);
  unsigned short* wprjt = (unsigned short*)(ws + 16121856);
  unsigned short* Qb    = (unsigned short*)(ws + 17301504);
  unsigned short* Kb    = (unsigned short*)(ws + 29884416);
  unsigned short* Vtb   = (unsigned short*)(ws + 42467328);
  unsigned*       cnt   = (unsigned*)(ws + 55050240);  // 128 u32

  cast_bf16_k<<<6144, 256, 0, stream>>>(x, xbf, (B_ * T_ * C_) / 4, cnt);
  tpose_cast_k<<<dim3((3 * C_) / 64, C_ / 64), 256, 0, stream>>>(Wqkv, wqkvt, C_, 3 * C_);
  tpose_cast_k<<<dim3(C_ / 64, C_ / 64), 256, 0, stream>>>(Wproj, wprjt, C_, C_);

  gemm_k<0><<<(B_ * T_ / 128) * (3 * C_ / 128), 256, 0, stream>>>(
      xbf, wqkvt, C_, Qb, Kb, Vtb, nullptr, nullptr);

  flash12_k<<<512, 256, 0, stream>>>(Qb, Kb, Vtb, xbf, cnt);

  gemm_k<1><<<(B_ * T_ / 128) * (C_ / 128), 256, 0, stream>>>(
      xbf, wprjt, C_, nullptr, nullptr, nullptr, out, bproj);
}

// Round 13
// 194.770 us; speedup vs baseline: 1.2561x; 1.2561x over previous
//
#include <hip/hip_runtime.h>

#define B_ 2
#define T_ 4096
#define C_ 768
#define H_ 12
#define D_ 64
#define QTASK 96       /* tasks per XCD queue: 3 bh * 32 qi */

typedef __attribute__((ext_vector_type(8))) short bf16x8;
typedef __attribute__((ext_vector_type(4))) float f32x4;
typedef __attribute__((ext_vector_type(16))) float f32x16;

__device__ __forceinline__ unsigned short f2bf(float f) {
  union { float f; unsigned u; } v; v.f = f;
  unsigned r = v.u + 0x7fffu + ((v.u >> 16) & 1u);
  return (unsigned short)(r >> 16);
}

__device__ __forceinline__ float exp2_hw(float x) {
  float r;
  asm("v_exp_f32 %0, %1" : "=v"(r) : "v"(x));
  return r;
}

__device__ __forceinline__ void gll16(const void* g, void* l) {
  __builtin_amdgcn_global_load_lds((const __attribute__((address_space(1))) void*)g,
                                   (__attribute__((address_space(3))) void*)l, 16, 0, 0);
}

#define MAX3(a, b, c) fmaxf(fmaxf((a), (b)), (c))

// ---------------- cast kernels ----------------

// f32 -> bf16 (coalesced); resets the 8 task-queue counters
__global__ __launch_bounds__(256) void cast_bf16_k(const float* __restrict__ in,
                                                   unsigned short* __restrict__ out, int n4,
                                                   unsigned* __restrict__ cnt) {
  int i = blockIdx.x * 256 + threadIdx.x;
  if (i < 128) cnt[i] = 0u;
  if (i >= n4) return;
  float4 v = ((const float4*)in)[i];
  union { unsigned short s[4]; unsigned long long u; } o;
  o.s[0] = f2bf(v.x); o.s[1] = f2bf(v.y); o.s[2] = f2bf(v.z); o.s[3] = f2bf(v.w);
  ((unsigned long long*)out)[i] = o.u;
}

// in [R][C] f32 -> out [C][R] bf16, 64x64 tiles via LDS (coalesced both sides)
__global__ __launch_bounds__(256) void tpose_cast_k(const float* __restrict__ in,
                                                    unsigned short* __restrict__ out,
                                                    int R, int C) {
  __shared__ unsigned short t[64][65];
  const int c0 = blockIdx.x * 64, r0 = blockIdx.y * 64;
  const int tr = threadIdx.x >> 6, tc = threadIdx.x & 63;
#pragma unroll
  for (int i = 0; i < 16; ++i) {
    int r = i * 4 + tr;
    t[r][tc] = f2bf(in[(size_t)(r0 + r) * C + c0 + tc]);
  }
  __syncthreads();
#pragma unroll
  for (int i = 0; i < 16; ++i) {
    int c = i * 4 + tr;
    out[(size_t)(c0 + c) * R + r0 + tc] = t[tc][c];
  }
}

// ---------------- GEMM1: 128x128 tile, scatter epilogue into Q/K/Vt ----------------

#define QSCALE 0.1803368801111243f /* 0.125 * log2(e) */

__global__ __launch_bounds__(256) void gemm_k(const unsigned short* __restrict__ A,
                                              const unsigned short* __restrict__ Bt,
                                              int K,
                                              unsigned short* __restrict__ q_out,
                                              unsigned short* __restrict__ k_out,
                                              unsigned short* __restrict__ vt_out) {
  __shared__ short a_lds[2][128 * 32];
  __shared__ short b_lds[2][128 * 32];
  const int tid = threadIdx.x;
  const int wave = tid >> 6, lane = tid & 63;
  const int wm = wave >> 1, wn = wave & 1;
  const int lr = lane & 15, lc = lane >> 4;

  const int id = blockIdx.x;
  const int xcd = id & 7, idc = id >> 3;
  const int bx = xcd * 8 + (idc & 7);
  const int by = idc >> 3;
  const int m0 = bx * 128, n0 = by * 128;

  f32x4 acc[4][4];
  for (int mi = 0; mi < 4; ++mi)
    for (int ni = 0; ni < 4; ++ni) acc[mi][ni] = (f32x4){0.f, 0.f, 0.f, 0.f};

  const unsigned short *ap[2], *bp[2];
  int lb[2];
#pragma unroll
  for (int p = 0; p < 2; ++p) {
    int chunk = p * 256 + wave * 64 + lane;
    int r = chunk >> 2, cc = chunk & 3;
    int c = cc ^ ((r >> 1) & 3);
    ap[p] = A + (size_t)(m0 + r) * K + c * 8;
    bp[p] = Bt + (size_t)(n0 + r) * K + c * 8;
    lb[p] = (p * 256 + wave * 64) * 8;
  }

  const int nks = K >> 5;
#pragma unroll
  for (int p = 0; p < 2; ++p) {
    gll16(ap[p], &a_lds[0][lb[p]]);
    gll16(bp[p], &b_lds[0][lb[p]]);
    ap[p] += 32; bp[p] += 32;
  }

  for (int ks = 0; ks < nks; ++ks) {
    const int buf = ks & 1;
    __builtin_amdgcn_s_barrier();
    __builtin_amdgcn_sched_barrier(0);
    if (ks + 1 < nks) {
#pragma unroll
      for (int p = 0; p < 2; ++p) {
        gll16(ap[p], &a_lds[buf ^ 1][lb[p]]);
        gll16(bp[p], &b_lds[buf ^ 1][lb[p]]);
        ap[p] += 32; bp[p] += 32;
      }
      asm volatile("s_waitcnt vmcnt(4)" ::: "memory");
    } else {
      asm volatile("s_waitcnt vmcnt(0)" ::: "memory");
    }
    __builtin_amdgcn_sched_barrier(0);
    __builtin_amdgcn_s_barrier();
    __builtin_amdgcn_sched_barrier(0);

    bf16x8 af[4], bfrag[4];
#pragma unroll
    for (int mi = 0; mi < 4; ++mi) {
      int r = wm * 64 + mi * 16 + lr;
      af[mi] = *(const bf16x8*)&a_lds[buf][r * 32 + (lc ^ ((r >> 1) & 3)) * 8];
    }
#pragma unroll
    for (int ni = 0; ni < 4; ++ni) {
      int r = wn * 64 + ni * 16 + lr;
      bfrag[ni] = *(const bf16x8*)&b_lds[buf][r * 32 + (lc ^ ((r >> 1) & 3)) * 8];
    }
    __builtin_amdgcn_s_setprio(1);
#pragma unroll
    for (int mi = 0; mi < 4; ++mi)
#pragma unroll
      for (int ni = 0; ni < 4; ++ni)
        acc[mi][ni] = __builtin_amdgcn_mfma_f32_16x16x32_bf16(af[mi], bfrag[ni], acc[mi][ni], 0, 0, 0);
    __builtin_amdgcn_s_setprio(0);
  }

  const int nn0 = n0 + wn * 64 + lr;
  const int which = n0 / 768;
#pragma unroll
  for (int mi = 0; mi < 4; ++mi)
#pragma unroll
    for (int ni = 0; ni < 4; ++ni) {
      int nn = nn0 + ni * 16;
      int rem = nn - which * 768;
      int h = rem >> 6, d = rem & 63;
      int t0v = m0 + wm * 64 + mi * 16 + lc * 4;
      int b = t0v >> 12, t = t0v & (T_ - 1);
      size_t bh = (size_t)(b * H_ + h);
      if (which == 2) {
        unsigned u0, u1;
        asm("v_cvt_pk_bf16_f32 %0, %1, %2" : "=v"(u0) : "v"(acc[mi][ni][0]), "v"(acc[mi][ni][1]));
        asm("v_cvt_pk_bf16_f32 %0, %1, %2" : "=v"(u1) : "v"(acc[mi][ni][2]), "v"(acc[mi][ni][3]));
        uint2 u = {u0, u1};
        *(uint2*)&vt_out[(bh * D_ + d) * T_ + t] = u;
      } else {
#pragma unroll
        for (int r = 0; r < 4; ++r) {
          float av = acc[mi][ni][r];
          if (which == 0) av *= QSCALE;
          unsigned short val = f2bf(av);
          if (which == 0) q_out[(bh * T_ + t + r) * D_ + d] = val;
          else            k_out[(bh * T_ + t + r) * D_ + d] = val;
        }
      }
    }
}

// ---------------- GEMM2: 64x128 tile (768 blocks -> 3/CU), f32 out + bias ----------------
// Same counted-vmcnt 2-phase structure; waves 2x2 of 32x64; 3 gll16/wave/step -> vmcnt(3).

__global__ __launch_bounds__(256) void gemm2_k(const unsigned short* __restrict__ A,
                                               const unsigned short* __restrict__ Bt,
                                               float* __restrict__ f_out,
                                               const float* __restrict__ bias) {
  __shared__ short a_lds[2][64 * 32];
  __shared__ short b_lds[2][128 * 32];
  const int tid = threadIdx.x;
  const int wave = tid >> 6, lane = tid & 63;
  const int wm = wave >> 1, wn = wave & 1;
  const int lr = lane & 15, lc = lane >> 4;
  const int K = C_;

  const int id = blockIdx.x;
  const int xcd = id & 7, idc = id >> 3;       // 768 blocks: idc 0..95
  const int bx = xcd * 16 + (idc & 15);        // 0..127 M-panels (64 rows each)
  const int by = idc >> 4;                     // 0..5  N-panels (128 cols each)
  const int m0 = bx * 64, n0 = by * 128;

  f32x4 acc[2][4];
  for (int mi = 0; mi < 2; ++mi)
    for (int ni = 0; ni < 4; ++ni) acc[mi][ni] = (f32x4){0.f, 0.f, 0.f, 0.f};

  // A: one round (64 rows x 4 chunks = 256); B: two rounds (128 rows)
  const unsigned short *apt, *bpt[2];
  int lba, lbb[2];
  {
    int chunk = wave * 64 + lane;
    int r = chunk >> 2, cc = chunk & 3;
    int c = cc ^ ((r >> 1) & 3);
    apt = A + (size_t)(m0 + r) * K + c * 8;
    lba = (wave * 64) * 8;
  }
#pragma unroll
  for (int p = 0; p < 2; ++p) {
    int chunk = p * 256 + wave * 64 + lane;
    int r = chunk >> 2, cc = chunk & 3;
    int c = cc ^ ((r >> 1) & 3);
    bpt[p] = Bt + (size_t)(n0 + r) * K + c * 8;
    lbb[p] = (p * 256 + wave * 64) * 8;
  }

  const int nks = K >> 5;  // 24
  gll16(apt, &a_lds[0][lba]); apt += 32;
#pragma unroll
  for (int p = 0; p < 2; ++p) { gll16(bpt[p], &b_lds[0][lbb[p]]); bpt[p] += 32; }

  for (int ks = 0; ks < nks; ++ks) {
    const int buf = ks & 1;
    __builtin_amdgcn_s_barrier();
    __builtin_amdgcn_sched_barrier(0);
    if (ks + 1 < nks) {
      gll16(apt, &a_lds[buf ^ 1][lba]); apt += 32;
#pragma unroll
      for (int p = 0; p < 2; ++p) { gll16(bpt[p], &b_lds[buf ^ 1][lbb[p]]); bpt[p] += 32; }
      asm volatile("s_waitcnt vmcnt(3)" ::: "memory");
    } else {
      asm volatile("s_waitcnt vmcnt(0)" ::: "memory");
    }
    __builtin_amdgcn_sched_barrier(0);
    __builtin_amdgcn_s_barrier();
    __builtin_amdgcn_sched_barrier(0);

    bf16x8 af[2], bfrag[4];
#pragma unroll
    for (int mi = 0; mi < 2; ++mi) {
      int r = wm * 32 + mi * 16 + lr;
      af[mi] = *(const bf16x8*)&a_lds[buf][r * 32 + (lc ^ ((r >> 1) & 3)) * 8];
    }
#pragma unroll
    for (int ni = 0; ni < 4; ++ni) {
      int r = wn * 64 + ni * 16 + lr;
      bfrag[ni] = *(const bf16x8*)&b_lds[buf][r * 32 + (lc ^ ((r >> 1) & 3)) * 8];
    }
    __builtin_amdgcn_s_setprio(1);
#pragma unroll
    for (int mi = 0; mi < 2; ++mi)
#pragma unroll
      for (int ni = 0; ni < 4; ++ni)
        acc[mi][ni] = __builtin_amdgcn_mfma_f32_16x16x32_bf16(af[mi], bfrag[ni], acc[mi][ni], 0, 0, 0);
    __builtin_amdgcn_s_setprio(0);
  }

#pragma unroll
  for (int mi = 0; mi < 2; ++mi)
#pragma unroll
    for (int ni = 0; ni < 4; ++ni) {
      int nn = n0 + wn * 64 + ni * 16 + lr;
      float bv = bias[nn];
#pragma unroll
      for (int r = 0; r < 4; ++r) {
        int m = m0 + wm * 32 + mi * 16 + lc * 4 + r;
        f_out[(size_t)m * C_ + nn] = acc[mi][ni][r] + bv;
      }
    }
}

// ---------------- flash attention v11 (R11 verbatim): KVBLK=128, SEQUENTIAL sub-tiles ----------------

#define PACK8(SV, PW, O)                                                          \
  do {                                                                            \
    unsigned w0, w1, w2, w3, w4, w5, w6, w7;                                      \
    asm("v_cvt_pk_bf16_f32 %0, %1, %2" : "=v"(w0) : "v"(SV[0]), "v"(SV[1]));      \
    asm("v_cvt_pk_bf16_f32 %0, %1, %2" : "=v"(w1) : "v"(SV[2]), "v"(SV[3]));      \
    asm("v_cvt_pk_bf16_f32 %0, %1, %2" : "=v"(w2) : "v"(SV[4]), "v"(SV[5]));      \
    asm("v_cvt_pk_bf16_f32 %0, %1, %2" : "=v"(w3) : "v"(SV[6]), "v"(SV[7]));      \
    asm("v_cvt_pk_bf16_f32 %0, %1, %2" : "=v"(w4) : "v"(SV[8]), "v"(SV[9]));      \
    asm("v_cvt_pk_bf16_f32 %0, %1, %2" : "=v"(w5) : "v"(SV[10]), "v"(SV[11]));    \
    asm("v_cvt_pk_bf16_f32 %0, %1, %2" : "=v"(w6) : "v"(SV[12]), "v"(SV[13]));    \
    asm("v_cvt_pk_bf16_f32 %0, %1, %2" : "=v"(w7) : "v"(SV[14]), "v"(SV[15]));    \
    asm("v_permlane32_swap_b32 %0, %1" : "+v"(w0), "+v"(w2));                     \
    asm("v_permlane32_swap_b32 %0, %1" : "+v"(w1), "+v"(w3));                     \
    asm("v_permlane32_swap_b32 %0, %1" : "+v"(w4), "+v"(w6));                     \
    asm("v_permlane32_swap_b32 %0, %1" : "+v"(w5), "+v"(w7));                     \
    PW[(O) + 0] = w0; PW[(O) + 1] = w1; PW[(O) + 2] = w2; PW[(O) + 3] = w3;       \
    PW[(O) + 4] = w4; PW[(O) + 5] = w5; PW[(O) + 6] = w6; PW[(O) + 7] = w7;       \
  } while (0)

__global__ __launch_bounds__(256) void flash11_k(const unsigned short* __restrict__ Qg,
                                                 const unsigned short* __restrict__ Kg,
                                                 const unsigned short* __restrict__ Vtg,
                                                 unsigned short* __restrict__ Og,
                                                 unsigned* __restrict__ cnt) {
  __shared__ short k_lds[2][16 * 512];   // 32 KB
  __shared__ short vt_lds[2][16 * 512];  // 32 KB
  __shared__ int task_s;

  const int tid = threadIdx.x;
  const int wave = tid >> 6, lane = tid & 63;
  const int lq = lane & 31, hi = lane >> 5;
  const int xq = blockIdx.x & 7;
  unsigned* myq = cnt + xq * 16;

  for (;;) {
    if (tid == 0) task_s = (int)atomicAdd(myq, 1u);
    __syncthreads();
    const int task = task_s;
    if (task >= QTASK) return;

    const int qi = 31 - task / 3;       // LPT: heavy first
    const int bh = xq * 3 + (task - (task / 3) * 3);
    const int qw = qi * 128 + wave * 32;
    const int q_g = qw + lq;

    const size_t kbase = (size_t)bh * T_ * D_;
    const size_t vbase = (size_t)bh * D_ * T_;

    const unsigned short* qrow = Qg + kbase + (size_t)q_g * D_;
    bf16x8 qf[4];
#pragma unroll
    for (int t = 0; t < 4; ++t) qf[t] = *(const bf16x8*)(qrow + t * 16 + hi * 8);

    f32x16 accT0, accT1;
#pragma unroll
    for (int r = 0; r < 16; ++r) { accT0[r] = 0.f; accT1[r] = 0.f; }
    float lvec[8];
#pragma unroll
    for (int r = 0; r < 8; ++r) lvec[r] = 0.f;
    float m = 0.f;

    const int nt = qi + 1;              // 128-key iterations

    const unsigned short *kb_p[4], *vb_p[4];
    int lf[4];
#pragma unroll
    for (int p = 0; p < 4; ++p) {
      int f = wave + p * 4;
      int sub = f >> 3, tt = (f >> 1) & 3, h = f & 1;
      kb_p[p] = Kg + kbase + (size_t)(sub * 64 + h * 32 + lq) * D_ + tt * 16 + hi * 8;
      vb_p[p] = Vtg + vbase + (size_t)(h * 32 + lq) * T_ + sub * 64 + tt * 16 + hi * 8;
      lf[p] = f * 512;
    }

    auto stage = [&](int it, int sb) {
#pragma unroll
      for (int p = 0; p < 4; ++p) {
        gll16(kb_p[p] + (size_t)it * 128 * D_, &k_lds[sb][lf[p]]);
        gll16(vb_p[p] + it * 128, &vt_lds[sb][lf[p]]);
      }
    };

    stage(0, 0);

    for (int j = 0; j < nt; ++j) {
      const int kv = j * 128;
      const int buf = j & 1;

      __builtin_amdgcn_s_barrier();
      __builtin_amdgcn_sched_barrier(0);
      if (j + 1 < nt) {
        stage(j + 1, buf ^ 1);
        asm volatile("s_waitcnt vmcnt(8)" ::: "memory");
      } else {
        asm volatile("s_waitcnt vmcnt(0)" ::: "memory");
      }
      __builtin_amdgcn_sched_barrier(0);
      __builtin_amdgcn_s_barrier();
      __builtin_amdgcn_sched_barrier(0);

      // ===== sub-tile 0 =====
      {
        const float negm = -m;
        f32x16 s0, s1;
#pragma unroll
        for (int r = 0; r < 16; ++r) { s0[r] = negm; s1[r] = negm; }
        __builtin_amdgcn_s_setprio(1);
#pragma unroll
        for (int t = 0; t < 4; ++t) {
          bf16x8 kf0 = *(const bf16x8*)&k_lds[buf][(t * 2 + 0) * 512 + lane * 8];
          bf16x8 kf1 = *(const bf16x8*)&k_lds[buf][(t * 2 + 1) * 512 + lane * 8];
          s0 = __builtin_amdgcn_mfma_f32_32x32x16_bf16(kf0, qf[t], s0, 0, 0, 0);
          s1 = __builtin_amdgcn_mfma_f32_32x32x16_bf16(kf1, qf[t], s1, 0, 0, 0);
        }
        __builtin_amdgcn_s_setprio(0);

        if (kv + 63 > qw) {
#pragma unroll
          for (int r = 0; r < 16; ++r) {
            int key0 = kv + ((r & 3) + 8 * (r >> 2) + 4 * hi);
            if (key0 > q_g) s0[r] = -INFINITY;
            if (key0 + 32 > q_g) s1[r] = -INFINITY;
          }
        }

        float mx[16];
#pragma unroll
        for (int r = 0; r < 16; ++r) mx[r] = fmaxf(s0[r], s1[r]);
        float a0 = MAX3(mx[0], mx[1], mx[2]);
        float a1 = MAX3(mx[3], mx[4], mx[5]);
        float a2 = MAX3(mx[6], mx[7], mx[8]);
        float a3 = MAX3(mx[9], mx[10], mx[11]);
        float a4 = MAX3(mx[12], mx[13], mx[14]);
        float rx = fmaxf(MAX3(a0, a1, a2), MAX3(a3, a4, mx[15]));
        rx = fmaxf(rx, __shfl_xor(rx, 32));

        if (!__all(rx <= 8.f)) {
          float dlt = fmaxf(rx, 0.f);
          float al = exp2_hw(-dlt);
          m += dlt;
#pragma unroll
          for (int r = 0; r < 16; ++r) { accT0[r] *= al; accT1[r] *= al; }
#pragma unroll
          for (int r = 0; r < 8; ++r) lvec[r] *= al;
#pragma unroll
          for (int r = 0; r < 16; ++r) { s0[r] -= dlt; s1[r] -= dlt; }
        }
#pragma unroll
        for (int r = 0; r < 16; ++r) s0[r] = exp2_hw(s0[r]);
#pragma unroll
        for (int r = 0; r < 16; ++r) s1[r] = exp2_hw(s1[r]);
#pragma unroll
        for (int r = 0; r < 8; ++r) lvec[r] += (s0[r] + s1[r]) + (s0[r + 8] + s1[r + 8]);

        union { unsigned u[16]; bf16x8 v[4]; } pwu;
        PACK8(s0, pwu.u, 0);
        PACK8(s1, pwu.u, 8);

        __builtin_amdgcn_s_setprio(1);
#pragma unroll
        for (int ks = 0; ks < 4; ++ks) {
          bf16x8 vf0 = *(const bf16x8*)&vt_lds[buf][(ks * 2 + 0) * 512 + lane * 8];
          bf16x8 vf1 = *(const bf16x8*)&vt_lds[buf][(ks * 2 + 1) * 512 + lane * 8];
          accT0 = __builtin_amdgcn_mfma_f32_32x32x16_bf16(vf0, pwu.v[ks], accT0, 0, 0, 0);
          accT1 = __builtin_amdgcn_mfma_f32_32x32x16_bf16(vf1, pwu.v[ks], accT1, 0, 0, 0);
        }
        __builtin_amdgcn_s_setprio(0);
      }

      // ===== sub-tile 1 (wave-uniform skip) =====
      if (kv + 64 <= qw + 31) {
        const float negm = -m;
        f32x16 s0, s1;
#pragma unroll
        for (int r = 0; r < 16; ++r) { s0[r] = negm; s1[r] = negm; }
        __builtin_amdgcn_s_setprio(1);
#pragma unroll
        for (int t = 0; t < 4; ++t) {
          bf16x8 kf0 = *(const bf16x8*)&k_lds[buf][(8 + t * 2 + 0) * 512 + lane * 8];
          bf16x8 kf1 = *(const bf16x8*)&k_lds[buf][(8 + t * 2 + 1) * 512 + lane * 8];
          s0 = __builtin_amdgcn_mfma_f32_32x32x16_bf16(kf0, qf[t], s0, 0, 0, 0);
          s1 = __builtin_amdgcn_mfma_f32_32x32x16_bf16(kf1, qf[t], s1, 0, 0, 0);
        }
        __builtin_amdgcn_s_setprio(0);

        if (kv + 127 > qw) {
#pragma unroll
          for (int r = 0; r < 16; ++r) {
            int key0 = kv + 64 + ((r & 3) + 8 * (r >> 2) + 4 * hi);
            if (key0 > q_g) s0[r] = -INFINITY;
            if (key0 + 32 > q_g) s1[r] = -INFINITY;
          }
        }

        float mx[16];
#pragma unroll
        for (int r = 0; r < 16; ++r) mx[r] = fmaxf(s0[r], s1[r]);
        float a0 = MAX3(mx[0], mx[1], mx[2]);
        float a1 = MAX3(mx[3], mx[4], mx[5]);
        float a2 = MAX3(mx[6], mx[7], mx[8]);
        float a3 = MAX3(mx[9], mx[10], mx[11]);
        float a4 = MAX3(mx[12], mx[13], mx[14]);
        float rx = fmaxf(MAX3(a0, a1, a2), MAX3(a3, a4, mx[15]));
        rx = fmaxf(rx, __shfl_xor(rx, 32));

        if (!__all(rx <= 8.f)) {
          float dlt = fmaxf(rx, 0.f);
          float al = exp2_hw(-dlt);
          m += dlt;
#pragma unroll
          for (int r = 0; r < 16; ++r) { accT0[r] *= al; accT1[r] *= al; }
#pragma unroll
          for (int r = 0; r < 8; ++r) lvec[r] *= al;
#pragma unroll
          for (int r = 0; r < 16; ++r) { s0[r] -= dlt; s1[r] -= dlt; }
        }
#pragma unroll
        for (int r = 0; r < 16; ++r) s0[r] = exp2_hw(s0[r]);
#pragma unroll
        for (int r = 0; r < 16; ++r) s1[r] = exp2_hw(s1[r]);
#pragma unroll
        for (int r = 0; r < 8; ++r) lvec[r] += (s0[r] + s1[r]) + (s0[r + 8] + s1[r + 8]);

        union { unsigned u[16]; bf16x8 v[4]; } pwu;
        PACK8(s0, pwu.u, 0);
        PACK8(s1, pwu.u, 8);

        __builtin_amdgcn_s_setprio(1);
#pragma unroll
        for (int ks = 0; ks < 4; ++ks) {
          bf16x8 vf0 = *(const bf16x8*)&vt_lds[buf][(8 + ks * 2 + 0) * 512 + lane * 8];
          bf16x8 vf1 = *(const bf16x8*)&vt_lds[buf][(8 + ks * 2 + 1) * 512 + lane * 8];
          accT0 = __builtin_amdgcn_mfma_f32_32x32x16_bf16(vf0, pwu.v[ks], accT0, 0, 0, 0);
          accT1 = __builtin_amdgcn_mfma_f32_32x32x16_bf16(vf1, pwu.v[ks], accT1, 0, 0, 0);
        }
        __builtin_amdgcn_s_setprio(0);
      }
    }

    // ---- final l reduce + epilogue ----
    float l = 0.f;
#pragma unroll
    for (int r = 0; r < 8; ++r) l += lvec[r];
    l += __shfl_xor(l, 32);
    const float inv = 1.0f / l;
    const int b = bh / H_, h = bh - b * H_;
    unsigned short* orow = Og + ((size_t)b * T_ + q_g) * C_ + h * D_;
#pragma unroll
    for (int g = 0; g < 4; ++g) {
      int d0 = 8 * g + 4 * hi;
      float e0 = accT0[4 * g + 0] * inv, e1 = accT0[4 * g + 1] * inv;
      float e2 = accT0[4 * g + 2] * inv, e3 = accT0[4 * g + 3] * inv;
      float f0 = accT1[4 * g + 0] * inv, f1 = accT1[4 * g + 1] * inv;
      float f2 = accT1[4 * g + 2] * inv, f3 = accT1[4 * g + 3] * inv;
      uint2 ua, ub;
      asm("v_cvt_pk_bf16_f32 %0, %1, %2" : "=v"(ua.x) : "v"(e0), "v"(e1));
      asm("v_cvt_pk_bf16_f32 %0, %1, %2" : "=v"(ua.y) : "v"(e2), "v"(e3));
      asm("v_cvt_pk_bf16_f32 %0, %1, %2" : "=v"(ub.x) : "v"(f0), "v"(f1));
      asm("v_cvt_pk_bf16_f32 %0, %1, %2" : "=v"(ub.y) : "v"(f2), "v"(f3));
      *(uint2*)(orow + d0) = ua;
      *(uint2*)(orow + 32 + d0) = ub;
    }
    __syncthreads();
  }
}

// ---------------- launcher ----------------

extern "C" void kernel_launch(void* const* d_in, const int* in_sizes, int n_in,
                              void* d_out, int out_size, void* d_ws, size_t ws_size,
                              hipStream_t stream) {
  const float* x     = (const float*)d_in[0];
  const float* Wqkv  = (const float*)d_in[1];
  const float* Wproj = (const float*)d_in[2];
  const float* bproj = (const float*)d_in[3];
  float* out = (float*)d_out;

  char* ws = (char*)d_ws;
  unsigned short* xbf   = (unsigned short*)(ws);
  unsigned short* wqkvt = (unsigned short*)(ws + 12582912);
  unsigned short* wprjt = (unsigned short*)(ws + 16121856);
  unsigned short* Qb    = (unsigned short*)(ws + 17301504);
  unsigned short* Kb    = (unsigned short*)(ws + 29884416);
  unsigned short* Vtb   = (unsigned short*)(ws + 42467328);
  unsigned*       cnt   = (unsigned*)(ws + 55050240);  // 128 u32

  cast_bf16_k<<<6144, 256, 0, stream>>>(x, xbf, (B_ * T_ * C_) / 4, cnt);
  tpose_cast_k<<<dim3((3 * C_) / 64, C_ / 64), 256, 0, stream>>>(Wqkv, wqkvt, C_, 3 * C_);
  tpose_cast_k<<<dim3(C_ / 64, C_ / 64), 256, 0, stream>>>(Wproj, wprjt, C_, C_);

  gemm_k<<<(B_ * T_ / 128) * (3 * C_ / 128), 256, 0, stream>>>(
      xbf, wqkvt, C_, Qb, Kb, Vtb);

  flash11_k<<<512, 256, 0, stream>>>(Qb, Kb, Vtb, xbf, cnt);

  gemm2_k<<<(B_ * T_ / 64) * (C_ / 128), 256, 0, stream>>>(xbf, wprjt, out, bproj);
}

// Round 14
// 194.072 us; speedup vs baseline: 1.2606x; 1.0036x over previous
//
#include <hip/hip_runtime.h>

#define B_ 2
#define T_ 4096
#define C_ 768
#define H_ 12
#define D_ 64
#define QTASK 96       /* tasks per XCD queue: 3 bh * 32 qi */

typedef __attribute__((ext_vector_type(8))) short bf16x8;
typedef __attribute__((ext_vector_type(4))) float f32x4;
typedef __attribute__((ext_vector_type(16))) float f32x16;

__device__ __forceinline__ unsigned short f2bf(float f) {
  union { float f; unsigned u; } v; v.f = f;
  unsigned r = v.u + 0x7fffu + ((v.u >> 16) & 1u);
  return (unsigned short)(r >> 16);
}

__device__ __forceinline__ float exp2_hw(float x) {
  float r;
  asm("v_exp_f32 %0, %1" : "=v"(r) : "v"(x));
  return r;
}

__device__ __forceinline__ void gll16(const void* g, void* l) {
  __builtin_amdgcn_global_load_lds((const __attribute__((address_space(1))) void*)g,
                                   (__attribute__((address_space(3))) void*)l, 16, 0, 0);
}

// ---------------- cast kernels ----------------

// f32 -> bf16 (coalesced); resets the 8 task-queue counters
__global__ __launch_bounds__(256) void cast_bf16_k(const float* __restrict__ in,
                                                   unsigned short* __restrict__ out, int n4,
                                                   unsigned* __restrict__ cnt) {
  int i = blockIdx.x * 256 + threadIdx.x;
  if (i < 128) cnt[i] = 0u;
  if (i >= n4) return;
  float4 v = ((const float4*)in)[i];
  union { unsigned short s[4]; unsigned long long u; } o;
  o.s[0] = f2bf(v.x); o.s[1] = f2bf(v.y); o.s[2] = f2bf(v.z); o.s[3] = f2bf(v.w);
  ((unsigned long long*)out)[i] = o.u;
}

// fused transpose-cast of BOTH weight matrices (64x64 tiles via LDS)
// blocks 0..431: Wqkv [768][2304] -> [2304][768]; 432..575: Wproj [768][768] -> [768][768]
__global__ __launch_bounds__(256) void tpose2_k(const float* __restrict__ a,
                                                unsigned short* __restrict__ ao,
                                                const float* __restrict__ b,
                                                unsigned short* __restrict__ bo) {
  __shared__ unsigned short t[64][65];
  int id = blockIdx.x;
  const float* in; unsigned short* out; int R, C, bx, by;
  if (id < 432) { in = a; out = ao; R = 768; C = 2304; bx = id % 36; by = id / 36; }
  else { id -= 432; in = b; out = bo; R = 768; C = 768; bx = id % 12; by = id / 12; }
  const int c0 = bx * 64, r0 = by * 64;
  const int tr = threadIdx.x >> 6, tc = threadIdx.x & 63;
#pragma unroll
  for (int i = 0; i < 16; ++i) {
    int r = i * 4 + tr;
    t[r][tc] = f2bf(in[(size_t)(r0 + r) * C + c0 + tc]);
  }
  __syncthreads();
#pragma unroll
  for (int i = 0; i < 16; ++i) {
    int c = i * 4 + tr;
    out[(size_t)(c0 + c) * R + r0 + tc] = t[tc][c];
  }
}

// ---------------- GEMM1: 128x128 tile, scatter epilogue into Q/K/Vt ----------------

#define QSCALE 0.1803368801111243f /* 0.125 * log2(e) */

__global__ __launch_bounds__(256) void gemm_k(const unsigned short* __restrict__ A,
                                              const unsigned short* __restrict__ Bt,
                                              int K,
                                              unsigned short* __restrict__ q_out,
                                              unsigned short* __restrict__ k_out,
                                              unsigned short* __restrict__ vt_out) {
  __shared__ short a_lds[2][128 * 32];
  __shared__ short b_lds[2][128 * 32];
  const int tid = threadIdx.x;
  const int wave = tid >> 6, lane = tid & 63;
  const int wm = wave >> 1, wn = wave & 1;
  const int lr = lane & 15, lc = lane >> 4;

  const int id = blockIdx.x;
  const int xcd = id & 7, idc = id >> 3;
  const int bx = xcd * 8 + (idc & 7);
  const int by = idc >> 3;
  const int m0 = bx * 128, n0 = by * 128;

  f32x4 acc[4][4];
  for (int mi = 0; mi < 4; ++mi)
    for (int ni = 0; ni < 4; ++ni) acc[mi][ni] = (f32x4){0.f, 0.f, 0.f, 0.f};

  const unsigned short *ap[2], *bp[2];
  int lb[2];
#pragma unroll
  for (int p = 0; p < 2; ++p) {
    int chunk = p * 256 + wave * 64 + lane;
    int r = chunk >> 2, cc = chunk & 3;
    int c = cc ^ ((r >> 1) & 3);
    ap[p] = A + (size_t)(m0 + r) * K + c * 8;
    bp[p] = Bt + (size_t)(n0 + r) * K + c * 8;
    lb[p] = (p * 256 + wave * 64) * 8;
  }

  const int nks = K >> 5;
#pragma unroll
  for (int p = 0; p < 2; ++p) {
    gll16(ap[p], &a_lds[0][lb[p]]);
    gll16(bp[p], &b_lds[0][lb[p]]);
    ap[p] += 32; bp[p] += 32;
  }

  for (int ks = 0; ks < nks; ++ks) {
    const int buf = ks & 1;
    __builtin_amdgcn_s_barrier();
    __builtin_amdgcn_sched_barrier(0);
    if (ks + 1 < nks) {
#pragma unroll
      for (int p = 0; p < 2; ++p) {
        gll16(ap[p], &a_lds[buf ^ 1][lb[p]]);
        gll16(bp[p], &b_lds[buf ^ 1][lb[p]]);
        ap[p] += 32; bp[p] += 32;
      }
      asm volatile("s_waitcnt vmcnt(4)" ::: "memory");
    } else {
      asm volatile("s_waitcnt vmcnt(0)" ::: "memory");
    }
    __builtin_amdgcn_sched_barrier(0);
    __builtin_amdgcn_s_barrier();
    __builtin_amdgcn_sched_barrier(0);

    bf16x8 af[4], bfrag[4];
#pragma unroll
    for (int mi = 0; mi < 4; ++mi) {
      int r = wm * 64 + mi * 16 + lr;
      af[mi] = *(const bf16x8*)&a_lds[buf][r * 32 + (lc ^ ((r >> 1) & 3)) * 8];
    }
#pragma unroll
    for (int ni = 0; ni < 4; ++ni) {
      int r = wn * 64 + ni * 16 + lr;
      bfrag[ni] = *(const bf16x8*)&b_lds[buf][r * 32 + (lc ^ ((r >> 1) & 3)) * 8];
    }
    __builtin_amdgcn_s_setprio(1);
#pragma unroll
    for (int mi = 0; mi < 4; ++mi)
#pragma unroll
      for (int ni = 0; ni < 4; ++ni)
        acc[mi][ni] = __builtin_amdgcn_mfma_f32_16x16x32_bf16(af[mi], bfrag[ni], acc[mi][ni], 0, 0, 0);
    __builtin_amdgcn_s_setprio(0);
  }

  const int nn0 = n0 + wn * 64 + lr;
  const int which = n0 / 768;
#pragma unroll
  for (int mi = 0; mi < 4; ++mi)
#pragma unroll
    for (int ni = 0; ni < 4; ++ni) {
      int nn = nn0 + ni * 16;
      int rem = nn - which * 768;
      int h = rem >> 6, d = rem & 63;
      int t0v = m0 + wm * 64 + mi * 16 + lc * 4;
      int b = t0v >> 12, t = t0v & (T_ - 1);
      size_t bh = (size_t)(b * H_ + h);
      if (which == 2) {
        unsigned u0, u1;
        asm("v_cvt_pk_bf16_f32 %0, %1, %2" : "=v"(u0) : "v"(acc[mi][ni][0]), "v"(acc[mi][ni][1]));
        asm("v_cvt_pk_bf16_f32 %0, %1, %2" : "=v"(u1) : "v"(acc[mi][ni][2]), "v"(acc[mi][ni][3]));
        uint2 u = {u0, u1};
        *(uint2*)&vt_out[(bh * D_ + d) * T_ + t] = u;
      } else {
#pragma unroll
        for (int r = 0; r < 4; ++r) {
          float av = acc[mi][ni][r];
          if (which == 0) av *= QSCALE;
          unsigned short val = f2bf(av);
          if (which == 0) q_out[(bh * T_ + t + r) * D_ + d] = val;
          else            k_out[(bh * T_ + t + r) * D_ + d] = val;
        }
      }
    }
}

// ---------------- GEMM2: 64x128 tile (768 blocks -> 3/CU), f32 out + bias ----------------

__global__ __launch_bounds__(256) void gemm2_k(const unsigned short* __restrict__ A,
                                               const unsigned short* __restrict__ Bt,
                                               float* __restrict__ f_out,
                                               const float* __restrict__ bias) {
  __shared__ short a_lds[2][64 * 32];
  __shared__ short b_lds[2][128 * 32];
  const int tid = threadIdx.x;
  const int wave = tid >> 6, lane = tid & 63;
  const int wm = wave >> 1, wn = wave & 1;
  const int lr = lane & 15, lc = lane >> 4;
  const int K = C_;

  const int id = blockIdx.x;
  const int xcd = id & 7, idc = id >> 3;
  const int bx = xcd * 16 + (idc & 15);
  const int by = idc >> 4;
  const int m0 = bx * 64, n0 = by * 128;

  f32x4 acc[2][4];
  for (int mi = 0; mi < 2; ++mi)
    for (int ni = 0; ni < 4; ++ni) acc[mi][ni] = (f32x4){0.f, 0.f, 0.f, 0.f};

  const unsigned short *apt, *bpt[2];
  int lba, lbb[2];
  {
    int chunk = wave * 64 + lane;
    int r = chunk >> 2, cc = chunk & 3;
    int c = cc ^ ((r >> 1) & 3);
    apt = A + (size_t)(m0 + r) * K + c * 8;
    lba = (wave * 64) * 8;
  }
#pragma unroll
  for (int p = 0; p < 2; ++p) {
    int chunk = p * 256 + wave * 64 + lane;
    int r = chunk >> 2, cc = chunk & 3;
    int c = cc ^ ((r >> 1) & 3);
    bpt[p] = Bt + (size_t)(n0 + r) * K + c * 8;
    lbb[p] = (p * 256 + wave * 64) * 8;
  }

  const int nks = K >> 5;
  gll16(apt, &a_lds[0][lba]); apt += 32;
#pragma unroll
  for (int p = 0; p < 2; ++p) { gll16(bpt[p], &b_lds[0][lbb[p]]); bpt[p] += 32; }

  for (int ks = 0; ks < nks; ++ks) {
    const int buf = ks & 1;
    __builtin_amdgcn_s_barrier();
    __builtin_amdgcn_sched_barrier(0);
    if (ks + 1 < nks) {
      gll16(apt, &a_lds[buf ^ 1][lba]); apt += 32;
#pragma unroll
      for (int p = 0; p < 2; ++p) { gll16(bpt[p], &b_lds[buf ^ 1][lbb[p]]); bpt[p] += 32; }
      asm volatile("s_waitcnt vmcnt(3)" ::: "memory");
    } else {
      asm volatile("s_waitcnt vmcnt(0)" ::: "memory");
    }
    __builtin_amdgcn_sched_barrier(0);
    __builtin_amdgcn_s_barrier();
    __builtin_amdgcn_sched_barrier(0);

    bf16x8 af[2], bfrag[4];
#pragma unroll
    for (int mi = 0; mi < 2; ++mi) {
      int r = wm * 32 + mi * 16 + lr;
      af[mi] = *(const bf16x8*)&a_lds[buf][r * 32 + (lc ^ ((r >> 1) & 3)) * 8];
    }
#pragma unroll
    for (int ni = 0; ni < 4; ++ni) {
      int r = wn * 64 + ni * 16 + lr;
      bfrag[ni] = *(const bf16x8*)&b_lds[buf][r * 32 + (lc ^ ((r >> 1) & 3)) * 8];
    }
    __builtin_amdgcn_s_setprio(1);
#pragma unroll
    for (int mi = 0; mi < 2; ++mi)
#pragma unroll
      for (int ni = 0; ni < 4; ++ni)
        acc[mi][ni] = __builtin_amdgcn_mfma_f32_16x16x32_bf16(af[mi], bfrag[ni], acc[mi][ni], 0, 0, 0);
    __builtin_amdgcn_s_setprio(0);
  }

#pragma unroll
  for (int mi = 0; mi < 2; ++mi)
#pragma unroll
    for (int ni = 0; ni < 4; ++ni) {
      int nn = n0 + wn * 64 + ni * 16 + lr;
      float bv = bias[nn];
#pragma unroll
      for (int r = 0; r < 4; ++r) {
        int m = m0 + wm * 32 + mi * 16 + lc * 4 + r;
        f_out[(size_t)m * C_ + nn] = acc[mi][ni][r] + bv;
      }
    }
}

// ---------------- flash attention v5 (R5 verbatim — best measured: ~130 us) ----------------
// Per-XCD queues (LPT), 1024 blocks (4/CU), counted-vmcnt double buffer.
// m folded into MFMA C-init; l kept as 16-reg lvec; frag-linear conflict-free LDS.

#define PACK8(SV, O)                                                              \
  do {                                                                            \
    unsigned w0, w1, w2, w3, w4, w5, w6, w7;                                      \
    asm("v_cvt_pk_bf16_f32 %0, %1, %2" : "=v"(w0) : "v"(SV[0]), "v"(SV[1]));      \
    asm("v_cvt_pk_bf16_f32 %0, %1, %2" : "=v"(w1) : "v"(SV[2]), "v"(SV[3]));      \
    asm("v_cvt_pk_bf16_f32 %0, %1, %2" : "=v"(w2) : "v"(SV[4]), "v"(SV[5]));      \
    asm("v_cvt_pk_bf16_f32 %0, %1, %2" : "=v"(w3) : "v"(SV[6]), "v"(SV[7]));      \
    asm("v_cvt_pk_bf16_f32 %0, %1, %2" : "=v"(w4) : "v"(SV[8]), "v"(SV[9]));      \
    asm("v_cvt_pk_bf16_f32 %0, %1, %2" : "=v"(w5) : "v"(SV[10]), "v"(SV[11]));    \
    asm("v_cvt_pk_bf16_f32 %0, %1, %2" : "=v"(w6) : "v"(SV[12]), "v"(SV[13]));    \
    asm("v_cvt_pk_bf16_f32 %0, %1, %2" : "=v"(w7) : "v"(SV[14]), "v"(SV[15]));    \
    asm("v_permlane32_swap_b32 %0, %1" : "+v"(w0), "+v"(w2));                     \
    asm("v_permlane32_swap_b32 %0, %1" : "+v"(w1), "+v"(w3));                     \
    asm("v_permlane32_swap_b32 %0, %1" : "+v"(w4), "+v"(w6));                     \
    asm("v_permlane32_swap_b32 %0, %1" : "+v"(w5), "+v"(w7));                     \
    pw[(O) + 0] = w0; pw[(O) + 1] = w1; pw[(O) + 2] = w2; pw[(O) + 3] = w3;       \
    pw[(O) + 4] = w4; pw[(O) + 5] = w5; pw[(O) + 6] = w6; pw[(O) + 7] = w7;       \
  } while (0)

__global__ __launch_bounds__(256) void flash5_k(const unsigned short* __restrict__ Qg,
                                                const unsigned short* __restrict__ Kg,
                                                const unsigned short* __restrict__ Vtg,
                                                unsigned short* __restrict__ Og,
                                                unsigned* __restrict__ cnt) {
  __shared__ short k_lds[2][8 * 512];
  __shared__ short vt_lds[2][8 * 512];
  __shared__ int task_s;

  const int tid = threadIdx.x;
  const int wave = tid >> 6, lane = tid & 63;
  const int lq = lane & 31, hi = lane >> 5;
  const int xq = blockIdx.x & 7;
  unsigned* myq = cnt + xq * 16;

  for (;;) {
    if (tid == 0) task_s = (int)atomicAdd(myq, 1u);
    __syncthreads();
    const int task = task_s;
    if (task >= QTASK) return;

    const int qi = 31 - task / 3;       // LPT: heavy first
    const int bh = xq * 3 + (task - (task / 3) * 3);
    const int qw = qi * 128 + wave * 32;
    const int q_g = qw + lq;

    const size_t kbase = (size_t)bh * T_ * D_;
    const size_t vbase = (size_t)bh * D_ * T_;

    const unsigned short* qrow = Qg + kbase + (size_t)q_g * D_;
    bf16x8 qf[4];
#pragma unroll
    for (int t = 0; t < 4; ++t) qf[t] = *(const bf16x8*)(qrow + t * 16 + hi * 8);

    f32x16 accT0, accT1;
#pragma unroll
    for (int r = 0; r < 16; ++r) { accT0[r] = 0.f; accT1[r] = 0.f; }
    float lvec[16];
#pragma unroll
    for (int r = 0; r < 16; ++r) lvec[r] = 0.f;
    float m = 0.f;  // safe: rescale triggers if any tile exceeds m+8

    const int nt = 2 * qi + 2;

    const unsigned short* kp = Kg + kbase + (size_t)((wave & 1) * 32 + lq) * D_ + (wave >> 1) * 16 + hi * 8;
    const unsigned short* vp = Vtg + vbase + (size_t)((wave & 1) * 32 + lq) * T_ + (wave >> 1) * 16 + hi * 8;
    const int lb0 = wave * 512, lb1 = (wave + 4) * 512;

    gll16(kp, &k_lds[0][lb0]); gll16(kp + 32, &k_lds[0][lb1]);
    gll16(vp, &vt_lds[0][lb0]); gll16(vp + 32, &vt_lds[0][lb1]);
    const unsigned short* kpn = kp + 64 * D_;
    const unsigned short* vpn = vp + 64;

    for (int it = 0; it < nt; ++it) {
      const int kv = it * 64;
      const int buf = it & 1;

      __builtin_amdgcn_s_barrier();
      __builtin_amdgcn_sched_barrier(0);
      if (it + 1 < nt) {
        gll16(kpn, &k_lds[buf ^ 1][lb0]); gll16(kpn + 32, &k_lds[buf ^ 1][lb1]);
        gll16(vpn, &vt_lds[buf ^ 1][lb0]); gll16(vpn + 32, &vt_lds[buf ^ 1][lb1]);
        kpn += 64 * D_; vpn += 64;
        asm volatile("s_waitcnt vmcnt(4)" ::: "memory");
      } else {
        asm volatile("s_waitcnt vmcnt(0)" ::: "memory");
      }
      __builtin_amdgcn_sched_barrier(0);
      __builtin_amdgcn_s_barrier();
      __builtin_amdgcn_sched_barrier(0);

      if (kv <= qw + 31) {
        // ---- S^T = K Q^T - m  (C-init = -m) ----
        const float negm = -m;
        f32x16 s0, s1;
#pragma unroll
        for (int r = 0; r < 16; ++r) { s0[r] = negm; s1[r] = negm; }
        __builtin_amdgcn_s_setprio(1);
#pragma unroll
        for (int t = 0; t < 4; ++t) {
          bf16x8 kf0 = *(const bf16x8*)&k_lds[buf][(t * 2 + 0) * 512 + lane * 8];
          bf16x8 kf1 = *(const bf16x8*)&k_lds[buf][(t * 2 + 1) * 512 + lane * 8];
          s0 = __builtin_amdgcn_mfma_f32_32x32x16_bf16(kf0, qf[t], s0, 0, 0, 0);
          s1 = __builtin_amdgcn_mfma_f32_32x32x16_bf16(kf1, qf[t], s1, 0, 0, 0);
        }
        __builtin_amdgcn_s_setprio(0);

        // ---- causal mask (diagonal tiles only) ----
        if (kv + 63 > qw) {
#pragma unroll
          for (int r = 0; r < 16; ++r) {
            int key0 = kv + ((r & 3) + 8 * (r >> 2) + 4 * hi);
            if (key0 > q_g) s0[r] = -INFINITY;
            if (key0 + 32 > q_g) s1[r] = -INFINITY;
          }
        }

        // ---- relative max (tree) ----
        float mx[16];
#pragma unroll
        for (int r = 0; r < 16; ++r) mx[r] = fmaxf(s0[r], s1[r]);
        float a0 = fmaxf(fmaxf(mx[0], mx[1]), mx[2]);
        float a1 = fmaxf(fmaxf(mx[3], mx[4]), mx[5]);
        float a2 = fmaxf(fmaxf(mx[6], mx[7]), mx[8]);
        float a3 = fmaxf(fmaxf(mx[9], mx[10]), mx[11]);
        float a4 = fmaxf(fmaxf(mx[12], mx[13]), mx[14]);
        float rx = fmaxf(fmaxf(fmaxf(a0, a1), fmaxf(a2, a3)), fmaxf(a4, mx[15]));
        rx = fmaxf(rx, __shfl_xor(rx, 32));

        if (!__all(rx <= 8.f)) {
          float dlt = fmaxf(rx, 0.f);
          float al = exp2_hw(-dlt);
          m += dlt;
#pragma unroll
          for (int r = 0; r < 16; ++r) { accT0[r] *= al; accT1[r] *= al; lvec[r] *= al; }
#pragma unroll
          for (int r = 0; r < 16; ++r) { s0[r] -= dlt; s1[r] -= dlt; }
        }
#pragma unroll
        for (int r = 0; r < 16; ++r) s0[r] = exp2_hw(s0[r]);
#pragma unroll
        for (int r = 0; r < 16; ++r) s1[r] = exp2_hw(s1[r]);
#pragma unroll
        for (int r = 0; r < 16; ++r) lvec[r] += s0[r] + s1[r];

        // ---- P^T -> bf16 B-frags ----
        unsigned pw[16];
        PACK8(s0, 0);
        PACK8(s1, 8);

        // ---- O^T += Vt P^T ----
        __builtin_amdgcn_s_setprio(1);
#pragma unroll
        for (int ks = 0; ks < 4; ++ks) {
          union { unsigned u[4]; bf16x8 v; } pb;
          pb.u[0] = pw[ks * 4 + 0]; pb.u[1] = pw[ks * 4 + 1];
          pb.u[2] = pw[ks * 4 + 2]; pb.u[3] = pw[ks * 4 + 3];
          bf16x8 vf0 = *(const bf16x8*)&vt_lds[buf][(ks * 2 + 0) * 512 + lane * 8];
          bf16x8 vf1 = *(const bf16x8*)&vt_lds[buf][(ks * 2 + 1) * 512 + lane * 8];
          accT0 = __builtin_amdgcn_mfma_f32_32x32x16_bf16(vf0, pb.v, accT0, 0, 0, 0);
          accT1 = __builtin_amdgcn_mfma_f32_32x32x16_bf16(vf1, pb.v, accT1, 0, 0, 0);
        }
        __builtin_amdgcn_s_setprio(0);
      }
    }

    // ---- final l reduce + epilogue ----
    float l = 0.f;
#pragma unroll
    for (int r = 0; r < 16; ++r) l += lvec[r];
    l += __shfl_xor(l, 32);
    const float inv = 1.0f / l;
    const int b = bh / H_, h = bh - b * H_;
    unsigned short* orow = Og + ((size_t)b * T_ + q_g) * C_ + h * D_;
#pragma unroll
    for (int g = 0; g < 4; ++g) {
      int d0 = 8 * g + 4 * hi;
      float e0 = accT0[4 * g + 0] * inv, e1 = accT0[4 * g + 1] * inv;
      float e2 = accT0[4 * g + 2] * inv, e3 = accT0[4 * g + 3] * inv;
      float f0 = accT1[4 * g + 0] * inv, f1 = accT1[4 * g + 1] * inv;
      float f2 = accT1[4 * g + 2] * inv, f3 = accT1[4 * g + 3] * inv;
      uint2 ua, ub;
      asm("v_cvt_pk_bf16_f32 %0, %1, %2" : "=v"(ua.x) : "v"(e0), "v"(e1));
      asm("v_cvt_pk_bf16_f32 %0, %1, %2" : "=v"(ua.y) : "v"(e2), "v"(e3));
      asm("v_cvt_pk_bf16_f32 %0, %1, %2" : "=v"(ub.x) : "v"(f0), "v"(f1));
      asm("v_cvt_pk_bf16_f32 %0, %1, %2" : "=v"(ub.y) : "v"(f2), "v"(f3));
      *(uint2*)(orow + d0) = ua;
      *(uint2*)(orow + 32 + d0) = ub;
    }
    __syncthreads();  // quiesce LDS before next pop
  }
}

// ---------------- launcher ----------------

extern "C" void kernel_launch(void* const* d_in, const int* in_sizes, int n_in,
                              void* d_out, int out_size, void* d_ws, size_t ws_size,
                              hipStream_t stream) {
  const float* x     = (const float*)d_in[0];
  const float* Wqkv  = (const float*)d_in[1];
  const float* Wproj = (const float*)d_in[2];
  const float* bproj = (const float*)d_in[3];
  float* out = (float*)d_out;

  char* ws = (char*)d_ws;
  unsigned short* xbf   = (unsigned short*)(ws);
  unsigned short* wqkvt = (unsigned short*)(ws + 12582912);
  unsigned short* wprjt = (unsigned short*)(ws + 16121856);
  unsigned short* Qb    = (unsigned short*)(ws + 17301504);
  unsigned short* Kb    = (unsigned short*)(ws + 29884416);
  unsigned short* Vtb   = (unsigned short*)(ws + 42467328);
  unsigned*       cnt   = (unsigned*)(ws + 55050240);  // 128 u32

  cast_bf16_k<<<6144, 256, 0, stream>>>(x, xbf, (B_ * T_ * C_) / 4, cnt);
  tpose2_k<<<576, 256, 0, stream>>>(Wqkv, wqkvt, Wproj, wprjt);

  gemm_k<<<(B_ * T_ / 128) * (3 * C_ / 128), 256, 0, stream>>>(
      xbf, wqkvt, C_, Qb, Kb, Vtb);

  flash5_k<<<1024, 256, 0, stream>>>(Qb, Kb, Vtb, xbf, cnt);

  gemm2_k<<<(B_ * T_ / 64) * (C_ / 128), 256, 0, stream>>>(xbf, wprjt, out, bproj);
}

// Round 15
// 193.585 us; speedup vs baseline: 1.2638x; 1.0025x over previous
//
#include <hip/hip_runtime.h>

#define B_ 2
#define T_ 4096
#define C_ 768
#define H_ 12
#define D_ 64
#define QTASK 144      /* per XCD queue: 3 bh * 48 (16 unsplit + 32 split halves) */

typedef __attribute__((ext_vector_type(8))) short bf16x8;
typedef __attribute__((ext_vector_type(4))) float f32x4;
typedef __attribute__((ext_vector_type(16))) float f32x16;

__device__ __forceinline__ unsigned short f2bf(float f) {
  union { float f; unsigned u; } v; v.f = f;
  unsigned r = v.u + 0x7fffu + ((v.u >> 16) & 1u);
  return (unsigned short)(r >> 16);
}

__device__ __forceinline__ float exp2_hw(float x) {
  float r;
  asm("v_exp_f32 %0, %1" : "=v"(r) : "v"(x));
  return r;
}

__device__ __forceinline__ void gll16(const void* g, void* l) {
  __builtin_amdgcn_global_load_lds((const __attribute__((address_space(1))) void*)g,
                                   (__attribute__((address_space(3))) void*)l, 16, 0, 0);
}

// ---------------- cast kernels ----------------

__global__ __launch_bounds__(256) void cast_bf16_k(const float* __restrict__ in,
                                                   unsigned short* __restrict__ out, int n4,
                                                   unsigned* __restrict__ cnt) {
  int i = blockIdx.x * 256 + threadIdx.x;
  if (i < 128) cnt[i] = 0u;
  if (i >= n4) return;
  float4 v = ((const float4*)in)[i];
  union { unsigned short s[4]; unsigned long long u; } o;
  o.s[0] = f2bf(v.x); o.s[1] = f2bf(v.y); o.s[2] = f2bf(v.z); o.s[3] = f2bf(v.w);
  ((unsigned long long*)out)[i] = o.u;
}

// fused transpose-cast of BOTH weight matrices (64x64 tiles via LDS)
__global__ __launch_bounds__(256) void tpose2_k(const float* __restrict__ a,
                                                unsigned short* __restrict__ ao,
                                                const float* __restrict__ b,
                                                unsigned short* __restrict__ bo) {
  __shared__ unsigned short t[64][65];
  int id = blockIdx.x;
  const float* in; unsigned short* out; int R, C, bx, by;
  if (id < 432) { in = a; out = ao; R = 768; C = 2304; bx = id % 36; by = id / 36; }
  else { id -= 432; in = b; out = bo; R = 768; C = 768; bx = id % 12; by = id / 12; }
  const int c0 = bx * 64, r0 = by * 64;
  const int tr = threadIdx.x >> 6, tc = threadIdx.x & 63;
#pragma unroll
  for (int i = 0; i < 16; ++i) {
    int r = i * 4 + tr;
    t[r][tc] = f2bf(in[(size_t)(r0 + r) * C + c0 + tc]);
  }
  __syncthreads();
#pragma unroll
  for (int i = 0; i < 16; ++i) {
    int c = i * 4 + tr;
    out[(size_t)(c0 + c) * R + r0 + tc] = t[tc][c];
  }
}

// ---------------- GEMM1: 128x128 tile, scatter epilogue into Q/K/Vt ----------------

#define QSCALE 0.1803368801111243f /* 0.125 * log2(e) */

__global__ __launch_bounds__(256) void gemm_k(const unsigned short* __restrict__ A,
                                              const unsigned short* __restrict__ Bt,
                                              int K,
                                              unsigned short* __restrict__ q_out,
                                              unsigned short* __restrict__ k_out,
                                              unsigned short* __restrict__ vt_out) {
  __shared__ short a_lds[2][128 * 32];
  __shared__ short b_lds[2][128 * 32];
  const int tid = threadIdx.x;
  const int wave = tid >> 6, lane = tid & 63;
  const int wm = wave >> 1, wn = wave & 1;
  const int lr = lane & 15, lc = lane >> 4;

  const int id = blockIdx.x;
  const int xcd = id & 7, idc = id >> 3;
  const int bx = xcd * 8 + (idc & 7);
  const int by = idc >> 3;
  const int m0 = bx * 128, n0 = by * 128;

  f32x4 acc[4][4];
  for (int mi = 0; mi < 4; ++mi)
    for (int ni = 0; ni < 4; ++ni) acc[mi][ni] = (f32x4){0.f, 0.f, 0.f, 0.f};

  const unsigned short *ap[2], *bp[2];
  int lb[2];
#pragma unroll
  for (int p = 0; p < 2; ++p) {
    int chunk = p * 256 + wave * 64 + lane;
    int r = chunk >> 2, cc = chunk & 3;
    int c = cc ^ ((r >> 1) & 3);
    ap[p] = A + (size_t)(m0 + r) * K + c * 8;
    bp[p] = Bt + (size_t)(n0 + r) * K + c * 8;
    lb[p] = (p * 256 + wave * 64) * 8;
  }

  const int nks = K >> 5;
#pragma unroll
  for (int p = 0; p < 2; ++p) {
    gll16(ap[p], &a_lds[0][lb[p]]);
    gll16(bp[p], &b_lds[0][lb[p]]);
    ap[p] += 32; bp[p] += 32;
  }

  for (int ks = 0; ks < nks; ++ks) {
    const int buf = ks & 1;
    __builtin_amdgcn_s_barrier();
    __builtin_amdgcn_sched_barrier(0);
    if (ks + 1 < nks) {
#pragma unroll
      for (int p = 0; p < 2; ++p) {
        gll16(ap[p], &a_lds[buf ^ 1][lb[p]]);
        gll16(bp[p], &b_lds[buf ^ 1][lb[p]]);
        ap[p] += 32; bp[p] += 32;
      }
      asm volatile("s_waitcnt vmcnt(4)" ::: "memory");
    } else {
      asm volatile("s_waitcnt vmcnt(0)" ::: "memory");
    }
    __builtin_amdgcn_sched_barrier(0);
    __builtin_amdgcn_s_barrier();
    __builtin_amdgcn_sched_barrier(0);

    bf16x8 af[4], bfrag[4];
#pragma unroll
    for (int mi = 0; mi < 4; ++mi) {
      int r = wm * 64 + mi * 16 + lr;
      af[mi] = *(const bf16x8*)&a_lds[buf][r * 32 + (lc ^ ((r >> 1) & 3)) * 8];
    }
#pragma unroll
    for (int ni = 0; ni < 4; ++ni) {
      int r = wn * 64 + ni * 16 + lr;
      bfrag[ni] = *(const bf16x8*)&b_lds[buf][r * 32 + (lc ^ ((r >> 1) & 3)) * 8];
    }
    __builtin_amdgcn_s_setprio(1);
#pragma unroll
    for (int mi = 0; mi < 4; ++mi)
#pragma unroll
      for (int ni = 0; ni < 4; ++ni)
        acc[mi][ni] = __builtin_amdgcn_mfma_f32_16x16x32_bf16(af[mi], bfrag[ni], acc[mi][ni], 0, 0, 0);
    __builtin_amdgcn_s_setprio(0);
  }

  const int nn0 = n0 + wn * 64 + lr;
  const int which = n0 / 768;
#pragma unroll
  for (int mi = 0; mi < 4; ++mi)
#pragma unroll
    for (int ni = 0; ni < 4; ++ni) {
      int nn = nn0 + ni * 16;
      int rem = nn - which * 768;
      int h = rem >> 6, d = rem & 63;
      int t0v = m0 + wm * 64 + mi * 16 + lc * 4;
      int b = t0v >> 12, t = t0v & (T_ - 1);
      size_t bh = (size_t)(b * H_ + h);
      if (which == 2) {
        unsigned u0, u1;
        asm("v_cvt_pk_bf16_f32 %0, %1, %2" : "=v"(u0) : "v"(acc[mi][ni][0]), "v"(acc[mi][ni][1]));
        asm("v_cvt_pk_bf16_f32 %0, %1, %2" : "=v"(u1) : "v"(acc[mi][ni][2]), "v"(acc[mi][ni][3]));
        uint2 u = {u0, u1};
        *(uint2*)&vt_out[(bh * D_ + d) * T_ + t] = u;
      } else {
#pragma unroll
        for (int r = 0; r < 4; ++r) {
          float av = acc[mi][ni][r];
          if (which == 0) av *= QSCALE;
          unsigned short val = f2bf(av);
          if (which == 0) q_out[(bh * T_ + t + r) * D_ + d] = val;
          else            k_out[(bh * T_ + t + r) * D_ + d] = val;
        }
      }
    }
}

// ---------------- GEMM2: 64x128 tile (768 blocks), f32 out + bias ----------------

__global__ __launch_bounds__(256) void gemm2_k(const unsigned short* __restrict__ A,
                                               const unsigned short* __restrict__ Bt,
                                               float* __restrict__ f_out,
                                               const float* __restrict__ bias) {
  __shared__ short a_lds[2][64 * 32];
  __shared__ short b_lds[2][128 * 32];
  const int tid = threadIdx.x;
  const int wave = tid >> 6, lane = tid & 63;
  const int wm = wave >> 1, wn = wave & 1;
  const int lr = lane & 15, lc = lane >> 4;
  const int K = C_;

  const int id = blockIdx.x;
  const int xcd = id & 7, idc = id >> 3;
  const int bx = xcd * 16 + (idc & 15);
  const int by = idc >> 4;
  const int m0 = bx * 64, n0 = by * 128;

  f32x4 acc[2][4];
  for (int mi = 0; mi < 2; ++mi)
    for (int ni = 0; ni < 4; ++ni) acc[mi][ni] = (f32x4){0.f, 0.f, 0.f, 0.f};

  const unsigned short *apt, *bpt[2];
  int lba, lbb[2];
  {
    int chunk = wave * 64 + lane;
    int r = chunk >> 2, cc = chunk & 3;
    int c = cc ^ ((r >> 1) & 3);
    apt = A + (size_t)(m0 + r) * K + c * 8;
    lba = (wave * 64) * 8;
  }
#pragma unroll
  for (int p = 0; p < 2; ++p) {
    int chunk = p * 256 + wave * 64 + lane;
    int r = chunk >> 2, cc = chunk & 3;
    int c = cc ^ ((r >> 1) & 3);
    bpt[p] = Bt + (size_t)(n0 + r) * K + c * 8;
    lbb[p] = (p * 256 + wave * 64) * 8;
  }

  const int nks = K >> 5;
  gll16(apt, &a_lds[0][lba]); apt += 32;
#pragma unroll
  for (int p = 0; p < 2; ++p) { gll16(bpt[p], &b_lds[0][lbb[p]]); bpt[p] += 32; }

  for (int ks = 0; ks < nks; ++ks) {
    const int buf = ks & 1;
    __builtin_amdgcn_s_barrier();
    __builtin_amdgcn_sched_barrier(0);
    if (ks + 1 < nks) {
      gll16(apt, &a_lds[buf ^ 1][lba]); apt += 32;
#pragma unroll
      for (int p = 0; p < 2; ++p) { gll16(bpt[p], &b_lds[buf ^ 1][lbb[p]]); bpt[p] += 32; }
      asm volatile("s_waitcnt vmcnt(3)" ::: "memory");
    } else {
      asm volatile("s_waitcnt vmcnt(0)" ::: "memory");
    }
    __builtin_amdgcn_sched_barrier(0);
    __builtin_amdgcn_s_barrier();
    __builtin_amdgcn_sched_barrier(0);

    bf16x8 af[2], bfrag[4];
#pragma unroll
    for (int mi = 0; mi < 2; ++mi) {
      int r = wm * 32 + mi * 16 + lr;
      af[mi] = *(const bf16x8*)&a_lds[buf][r * 32 + (lc ^ ((r >> 1) & 3)) * 8];
    }
#pragma unroll
    for (int ni = 0; ni < 4; ++ni) {
      int r = wn * 64 + ni * 16 + lr;
      bfrag[ni] = *(const bf16x8*)&b_lds[buf][r * 32 + (lc ^ ((r >> 1) & 3)) * 8];
    }
    __builtin_amdgcn_s_setprio(1);
#pragma unroll
    for (int mi = 0; mi < 2; ++mi)
#pragma unroll
      for (int ni = 0; ni < 4; ++ni)
        acc[mi][ni] = __builtin_amdgcn_mfma_f32_16x16x32_bf16(af[mi], bfrag[ni], acc[mi][ni], 0, 0, 0);
    __builtin_amdgcn_s_setprio(0);
  }

#pragma unroll
  for (int mi = 0; mi < 2; ++mi)
#pragma unroll
    for (int ni = 0; ni < 4; ++ni) {
      int nn = n0 + wn * 64 + ni * 16 + lr;
      float bv = bias[nn];
#pragma unroll
      for (int r = 0; r < 4; ++r) {
        int m = m0 + wm * 32 + mi * 16 + lc * 4 + r;
        f_out[(size_t)m * C_ + nn] = acc[mi][ni][r] + bv;
      }
    }
}

// ---------------- flash v14: flash5 + split-KV partials (merge in separate kernel) ----------------
// Task table per bh: 16 unsplit (qi 0..15) + 32 halves (qi 16..31), ~LPT order.
// Encode: bit7 split, bit6 half, bits5..0 qi. Max task = 33 tiles (vs 64 unsplit).
__device__ const unsigned char g_tasktbl[48] = {
  15, 0x80|31, 0xC0|31,
      0x80|30, 0xC0|30,
  14, 0x80|29, 0xC0|29,
      0x80|28, 0xC0|28,
  13, 0x80|27, 0xC0|27,
      0x80|26, 0xC0|26,
  12, 0x80|25, 0xC0|25,
      0x80|24, 0xC0|24,
  11, 0x80|23, 0xC0|23,
      0x80|22, 0xC0|22,
  10, 0x80|21, 0xC0|21,
      0x80|20, 0xC0|20,
   9, 0x80|19, 0xC0|19,
      0x80|18, 0xC0|18,
   8, 0x80|17, 0xC0|17,
      0x80|16, 0xC0|16,
   7, 6, 5, 4, 3, 2, 1, 0
};

#define PACK8(SV, O)                                                              \
  do {                                                                            \
    unsigned w0, w1, w2, w3, w4, w5, w6, w7;                                      \
    asm("v_cvt_pk_bf16_f32 %0, %1, %2" : "=v"(w0) : "v"(SV[0]), "v"(SV[1]));      \
    asm("v_cvt_pk_bf16_f32 %0, %1, %2" : "=v"(w1) : "v"(SV[2]), "v"(SV[3]));      \
    asm("v_cvt_pk_bf16_f32 %0, %1, %2" : "=v"(w2) : "v"(SV[4]), "v"(SV[5]));      \
    asm("v_cvt_pk_bf16_f32 %0, %1, %2" : "=v"(w3) : "v"(SV[6]), "v"(SV[7]));      \
    asm("v_cvt_pk_bf16_f32 %0, %1, %2" : "=v"(w4) : "v"(SV[8]), "v"(SV[9]));      \
    asm("v_cvt_pk_bf16_f32 %0, %1, %2" : "=v"(w5) : "v"(SV[10]), "v"(SV[11]));    \
    asm("v_cvt_pk_bf16_f32 %0, %1, %2" : "=v"(w6) : "v"(SV[12]), "v"(SV[13]));    \
    asm("v_cvt_pk_bf16_f32 %0, %1, %2" : "=v"(w7) : "v"(SV[14]), "v"(SV[15]));    \
    asm("v_permlane32_swap_b32 %0, %1" : "+v"(w0), "+v"(w2));                     \
    asm("v_permlane32_swap_b32 %0, %1" : "+v"(w1), "+v"(w3));                     \
    asm("v_permlane32_swap_b32 %0, %1" : "+v"(w4), "+v"(w6));                     \
    asm("v_permlane32_swap_b32 %0, %1" : "+v"(w5), "+v"(w7));                     \
    pw[(O) + 0] = w0; pw[(O) + 1] = w1; pw[(O) + 2] = w2; pw[(O) + 3] = w3;       \
    pw[(O) + 4] = w4; pw[(O) + 5] = w5; pw[(O) + 6] = w6; pw[(O) + 7] = w7;       \
  } while (0)

__global__ __launch_bounds__(256) void flash14_k(const unsigned short* __restrict__ Qg,
                                                 const unsigned short* __restrict__ Kg,
                                                 const unsigned short* __restrict__ Vtg,
                                                 unsigned short* __restrict__ Og,
                                                 unsigned* __restrict__ cnt,
                                                 unsigned short* __restrict__ part) {
  __shared__ short k_lds[2][8 * 512];
  __shared__ short vt_lds[2][8 * 512];
  __shared__ int task_s;

  const int tid = threadIdx.x;
  const int wave = tid >> 6, lane = tid & 63;
  const int lq = lane & 31, hi = lane >> 5;
  const int xq = blockIdx.x & 7;
  unsigned* myq = cnt + xq * 16;

  for (;;) {
    if (tid == 0) task_s = (int)atomicAdd(myq, 1u);
    __syncthreads();
    const int task = task_s;
    if (task >= QTASK) return;

    const int d3 = task / 3;
    const int desc = g_tasktbl[d3];
    const int qi = desc & 63;
    const int split = desc >> 7;
    const int half = (desc >> 6) & 1;
    const int bh = xq * 3 + (task - d3 * 3);
    const int qw = qi * 128 + wave * 32;
    const int q_g = qw + lq;

    const int it0 = (split && half) ? (qi + 1) : 0;
    const int itN = split ? (half ? (2 * qi + 2) : (qi + 1)) : (2 * qi + 2);
    const int ntl = itN - it0;

    const size_t kbase = (size_t)bh * T_ * D_;
    const size_t vbase = (size_t)bh * D_ * T_;

    const unsigned short* qrow = Qg + kbase + (size_t)q_g * D_;
    bf16x8 qf[4];
#pragma unroll
    for (int t = 0; t < 4; ++t) qf[t] = *(const bf16x8*)(qrow + t * 16 + hi * 8);

    f32x16 accT0, accT1;
#pragma unroll
    for (int r = 0; r < 16; ++r) { accT0[r] = 0.f; accT1[r] = 0.f; }
    float lvec[16];
#pragma unroll
    for (int r = 0; r < 16; ++r) lvec[r] = 0.f;
    float m = 0.f;

    const unsigned short* kp = Kg + kbase + (size_t)((wave & 1) * 32 + lq) * D_ +
                               (wave >> 1) * 16 + hi * 8 + (size_t)it0 * 64 * D_;
    const unsigned short* vp = Vtg + vbase + (size_t)((wave & 1) * 32 + lq) * T_ +
                               (wave >> 1) * 16 + hi * 8 + it0 * 64;
    const int lb0 = wave * 512, lb1 = (wave + 4) * 512;

    gll16(kp, &k_lds[0][lb0]); gll16(kp + 32, &k_lds[0][lb1]);
    gll16(vp, &vt_lds[0][lb0]); gll16(vp + 32, &vt_lds[0][lb1]);
    const unsigned short* kpn = kp + 64 * D_;
    const unsigned short* vpn = vp + 64;

    for (int j = 0; j < ntl; ++j) {
      const int kv = (it0 + j) * 64;
      const int buf = j & 1;

      __builtin_amdgcn_s_barrier();
      __builtin_amdgcn_sched_barrier(0);
      if (j + 1 < ntl) {
        gll16(kpn, &k_lds[buf ^ 1][lb0]); gll16(kpn + 32, &k_lds[buf ^ 1][lb1]);
        gll16(vpn, &vt_lds[buf ^ 1][lb0]); gll16(vpn + 32, &vt_lds[buf ^ 1][lb1]);
        kpn += 64 * D_; vpn += 64;
        asm volatile("s_waitcnt vmcnt(4)" ::: "memory");
      } else {
        asm volatile("s_waitcnt vmcnt(0)" ::: "memory");
      }
      __builtin_amdgcn_sched_barrier(0);
      __builtin_amdgcn_s_barrier();
      __builtin_amdgcn_sched_barrier(0);

      if (kv <= qw + 31) {
        const float negm = -m;
        f32x16 s0, s1;
#pragma unroll
        for (int r = 0; r < 16; ++r) { s0[r] = negm; s1[r] = negm; }
        __builtin_amdgcn_s_setprio(1);
#pragma unroll
        for (int t = 0; t < 4; ++t) {
          bf16x8 kf0 = *(const bf16x8*)&k_lds[buf][(t * 2 + 0) * 512 + lane * 8];
          bf16x8 kf1 = *(const bf16x8*)&k_lds[buf][(t * 2 + 1) * 512 + lane * 8];
          s0 = __builtin_amdgcn_mfma_f32_32x32x16_bf16(kf0, qf[t], s0, 0, 0, 0);
          s1 = __builtin_amdgcn_mfma_f32_32x32x16_bf16(kf1, qf[t], s1, 0, 0, 0);
        }
        __builtin_amdgcn_s_setprio(0);

        if (kv + 63 > qw) {
#pragma unroll
          for (int r = 0; r < 16; ++r) {
            int key0 = kv + ((r & 3) + 8 * (r >> 2) + 4 * hi);
            if (key0 > q_g) s0[r] = -INFINITY;
            if (key0 + 32 > q_g) s1[r] = -INFINITY;
          }
        }

        float mx[16];
#pragma unroll
        for (int r = 0; r < 16; ++r) mx[r] = fmaxf(s0[r], s1[r]);
        float a0 = fmaxf(fmaxf(mx[0], mx[1]), mx[2]);
        float a1 = fmaxf(fmaxf(mx[3], mx[4]), mx[5]);
        float a2 = fmaxf(fmaxf(mx[6], mx[7]), mx[8]);
        float a3 = fmaxf(fmaxf(mx[9], mx[10]), mx[11]);
        float a4 = fmaxf(fmaxf(mx[12], mx[13]), mx[14]);
        float rx = fmaxf(fmaxf(fmaxf(a0, a1), fmaxf(a2, a3)), fmaxf(a4, mx[15]));
        rx = fmaxf(rx, __shfl_xor(rx, 32));

        if (!__all(rx <= 8.f)) {
          float dlt = fmaxf(rx, 0.f);
          float al = exp2_hw(-dlt);
          m += dlt;
#pragma unroll
          for (int r = 0; r < 16; ++r) { accT0[r] *= al; accT1[r] *= al; lvec[r] *= al; }
#pragma unroll
          for (int r = 0; r < 16; ++r) { s0[r] -= dlt; s1[r] -= dlt; }
        }
#pragma unroll
        for (int r = 0; r < 16; ++r) s0[r] = exp2_hw(s0[r]);
#pragma unroll
        for (int r = 0; r < 16; ++r) s1[r] = exp2_hw(s1[r]);
#pragma unroll
        for (int r = 0; r < 16; ++r) lvec[r] += s0[r] + s1[r];

        unsigned pw[16];
        PACK8(s0, 0);
        PACK8(s1, 8);

        __builtin_amdgcn_s_setprio(1);
#pragma unroll
        for (int ks = 0; ks < 4; ++ks) {
          union { unsigned u[4]; bf16x8 v; } pb;
          pb.u[0] = pw[ks * 4 + 0]; pb.u[1] = pw[ks * 4 + 1];
          pb.u[2] = pw[ks * 4 + 2]; pb.u[3] = pw[ks * 4 + 3];
          bf16x8 vf0 = *(const bf16x8*)&vt_lds[buf][(ks * 2 + 0) * 512 + lane * 8];
          bf16x8 vf1 = *(const bf16x8*)&vt_lds[buf][(ks * 2 + 1) * 512 + lane * 8];
          accT0 = __builtin_amdgcn_mfma_f32_32x32x16_bf16(vf0, pb.v, accT0, 0, 0, 0);
          accT1 = __builtin_amdgcn_mfma_f32_32x32x16_bf16(vf1, pb.v, accT1, 0, 0, 0);
        }
        __builtin_amdgcn_s_setprio(0);
      }
    }

    // ---- l reduce ----
    float l = 0.f;
#pragma unroll
    for (int r = 0; r < 16; ++r) l += lvec[r];
    l += __shfl_xor(l, 32);

    if (!split) {
      // direct write (unchanged from flash5)
      const float inv = 1.0f / l;
      const int b = bh / H_, h = bh - b * H_;
      unsigned short* orow = Og + ((size_t)b * T_ + q_g) * C_ + h * D_;
#pragma unroll
      for (int g = 0; g < 4; ++g) {
        int d0 = 8 * g + 4 * hi;
        float e0 = accT0[4 * g + 0] * inv, e1 = accT0[4 * g + 1] * inv;
        float e2 = accT0[4 * g + 2] * inv, e3 = accT0[4 * g + 3] * inv;
        float f0 = accT1[4 * g + 0] * inv, f1 = accT1[4 * g + 1] * inv;
        float f2 = accT1[4 * g + 2] * inv, f3 = accT1[4 * g + 3] * inv;
        uint2 ua, ub;
        asm("v_cvt_pk_bf16_f32 %0, %1, %2" : "=v"(ua.x) : "v"(e0), "v"(e1));
        asm("v_cvt_pk_bf16_f32 %0, %1, %2" : "=v"(ua.y) : "v"(e2), "v"(e3));
        asm("v_cvt_pk_bf16_f32 %0, %1, %2" : "=v"(ub.x) : "v"(f0), "v"(f1));
        asm("v_cvt_pk_bf16_f32 %0, %1, %2" : "=v"(ub.y) : "v"(f2), "v"(f3));
        *(uint2*)(orow + d0) = ua;
        *(uint2*)(orow + 32 + d0) = ub;
      }
    } else {
      // partial write: unnormalized accT (bf16) + (m,l) f32, 18432 B sub-slot
      unsigned short* pbase = part + (size_t)((bh * 16 + (qi - 16)) * 2 + half) * 9216;
      unsigned w[16];
#pragma unroll
      for (int g = 0; g < 8; ++g)
        asm("v_cvt_pk_bf16_f32 %0, %1, %2" : "=v"(w[g]) : "v"(accT0[2 * g]), "v"(accT0[2 * g + 1]));
#pragma unroll
      for (int g = 0; g < 8; ++g)
        asm("v_cvt_pk_bf16_f32 %0, %1, %2" : "=v"(w[8 + g]) : "v"(accT1[2 * g]), "v"(accT1[2 * g + 1]));
      uint4* po = (uint4*)(pbase + tid * 32);
#pragma unroll
      for (int g = 0; g < 4; ++g) {
        uint4 u = {w[4 * g + 0], w[4 * g + 1], w[4 * g + 2], w[4 * g + 3]};
        po[g] = u;
      }
      float2 ml = {m, l};
      ((float2*)(pbase + 8192))[tid] = ml;
    }
    __syncthreads();  // quiesce LDS before next pop
  }
}

// ---------------- merge kernel: combine the two halves of each split task ----------------
__global__ __launch_bounds__(256) void merge_k(const unsigned short* __restrict__ part,
                                               unsigned short* __restrict__ Og) {
  const int slot = blockIdx.x;             // 0..383
  const int bh = slot >> 4, qi = (slot & 15) + 16;
  const int tid = threadIdx.x;
  const int wave = tid >> 6, lane = tid & 63;
  const int lq = lane & 31, hi = lane >> 5;

  const unsigned short* pa = part + (size_t)(slot * 2 + 0) * 9216;
  const unsigned short* pb = part + (size_t)(slot * 2 + 1) * 9216;
  float2 mla = ((const float2*)(pa + 8192))[tid];
  float2 mlb = ((const float2*)(pb + 8192))[tid];
  float newm = fmaxf(mla.x, mlb.x);
  float sa = exp2_hw(mla.x - newm), sb = exp2_hw(mlb.x - newm);
  float l = mla.y * sa + mlb.y * sb;
  float inv = 1.0f / l;

  const uint4* qa = (const uint4*)(pa + tid * 32);
  const uint4* qb = (const uint4*)(pb + tid * 32);
  float o[32];
#pragma unroll
  for (int g = 0; g < 4; ++g) {
    uint4 ua = qa[g], ub = qb[g];
#pragma unroll
    for (int e = 0; e < 4; ++e) {
      unsigned wa = ((const unsigned*)&ua)[e];
      unsigned wb = ((const unsigned*)&ub)[e];
      union { unsigned u; float f; } la_, ha_, lb_, hb_;
      la_.u = wa << 16; ha_.u = wa & 0xffff0000u;
      lb_.u = wb << 16; hb_.u = wb & 0xffff0000u;
      int r = g * 8 + e * 2;
      o[r]     = la_.f * sa + lb_.f * sb;
      o[r + 1] = ha_.f * sa + hb_.f * sb;
    }
  }

  const int q_g = qi * 128 + wave * 32 + lq;
  const int b = bh / H_, h = bh - b * H_;
  unsigned short* orow = Og + ((size_t)b * T_ + q_g) * C_ + h * D_;
#pragma unroll
  for (int g = 0; g < 4; ++g) {
    int d0 = 8 * g + 4 * hi;
    float e0 = o[4 * g + 0] * inv, e1 = o[4 * g + 1] * inv;
    float e2 = o[4 * g + 2] * inv, e3 = o[4 * g + 3] * inv;
    float f0 = o[16 + 4 * g + 0] * inv, f1 = o[16 + 4 * g + 1] * inv;
    float f2 = o[16 + 4 * g + 2] * inv, f3 = o[16 + 4 * g + 3] * inv;
    uint2 ua, ub;
    asm("v_cvt_pk_bf16_f32 %0, %1, %2" : "=v"(ua.x) : "v"(e0), "v"(e1));
    asm("v_cvt_pk_bf16_f32 %0, %1, %2" : "=v"(ua.y) : "v"(e2), "v"(e3));
    asm("v_cvt_pk_bf16_f32 %0, %1, %2" : "=v"(ub.x) : "v"(f0), "v"(f1));
    asm("v_cvt_pk_bf16_f32 %0, %1, %2" : "=v"(ub.y) : "v"(f2), "v"(f3));
    *(uint2*)(orow + d0) = ua;
    *(uint2*)(orow + 32 + d0) = ub;
  }
}

// ---------------- launcher ----------------

extern "C" void kernel_launch(void* const* d_in, const int* in_sizes, int n_in,
                              void* d_out, int out_size, void* d_ws, size_t ws_size,
                              hipStream_t stream) {
  const float* x     = (const float*)d_in[0];
  const float* Wqkv  = (const float*)d_in[1];
  const float* Wproj = (const float*)d_in[2];
  const float* bproj = (const float*)d_in[3];
  float* out = (float*)d_out;

  char* ws = (char*)d_ws;
  unsigned short* xbf   = (unsigned short*)(ws);
  unsigned short* wqkvt = (unsigned short*)(ws + 12582912);
  unsigned short* wprjt = (unsigned short*)(ws + 16121856);
  unsigned short* Qb    = (unsigned short*)(ws + 17301504);
  unsigned short* Kb    = (unsigned short*)(ws + 29884416);
  unsigned short* Vtb   = (unsigned short*)(ws + 42467328);
  unsigned*       cnt   = (unsigned*)(ws + 55050240);       // 128 u32
  unsigned short* part  = (unsigned short*)(ws + 55052288); // 384*2*18432 B

  cast_bf16_k<<<6144, 256, 0, stream>>>(x, xbf, (B_ * T_ * C_) / 4, cnt);
  tpose2_k<<<576, 256, 0, stream>>>(Wqkv, wqkvt, Wproj, wprjt);

  gemm_k<<<(B_ * T_ / 128) * (3 * C_ / 128), 256, 0, stream>>>(
      xbf, wqkvt, C_, Qb, Kb, Vtb);

  flash14_k<<<1024, 256, 0, stream>>>(Qb, Kb, Vtb, xbf, cnt, part);
  merge_k<<<384, 256, 0, stream>>>(part, xbf);

  gemm2_k<<<(B_ * T_ / 64) * (C_ / 128), 256, 0, stream>>>(xbf, wprjt, out, bproj);
}